// Round 13
// baseline (780.144 us; speedup 1.0000x reference)
//
#include <hip/hip_runtime.h>
#include <hip/hip_bf16.h>

#define NNODE 16384

typedef short v8s __attribute__((ext_vector_type(8)));
typedef float v4f __attribute__((ext_vector_type(4)));
typedef unsigned short us16;

__device__ __forceinline__ us16 f2bf(float v) {
    unsigned u = __float_as_uint(v);
    unsigned r = (u + 0x7FFF + ((u >> 16) & 1)) >> 16;
    return (us16)r;
}
__device__ __forceinline__ float bf2f(us16 s) {
    return __uint_as_float(((unsigned)s) << 16);
}

// ======================= split-bf16 MFMA GEMM v9 =======================
// A in LDS (hi/lo, XOR swizzle), BM=64, NB col-groups of 64, 4 waves (2x2).
// Reg-prefetch pipeline; B in MFMA fragment order (coalesced per-wave loads).
// XCD-chunked 1-D grid swizzle (nwg%8==0). Optional fused BN-stats (STATS=1):
// per-block column sum/sumsq -> part[rowblk][col] (deterministic).
// 3-term split: AhBh + AlBh + AhBl. ACC: += f32 CfIn. OUT: 0=f32, 1=split bf16.
template<int EPI, int OUT, int ACC, int NB, int STATS>
__global__ __launch_bounds__(256, 4)
void mgemm9(int nyPanels,
            const us16* __restrict__ Ah, const us16* __restrict__ Al,
            int ldA, int K,
            const us16* __restrict__ Bh, const us16* __restrict__ Bl, int KC,
            const float* __restrict__ CfIn, int ldCin,
            float* __restrict__ Cf, us16* __restrict__ Ch, us16* __restrict__ Cl,
            int ldC, int Ncol, const float* __restrict__ bias,
            float* __restrict__ statsPart, int statsStride)
{
    __shared__ __align__(16) us16 AhS[64 * 64];
    __shared__ __align__(16) us16 AlS[64 * 64];
    const int nwg = gridDim.x;
    const int bid = blockIdx.x;
    const int wgid = (bid & 7) * (nwg >> 3) + (bid >> 3);   // XCD-chunked (nwg%8==0)
    const int bm  = (wgid / nyPanels) * 64;
    const int bn0 = (wgid % nyPanels) * (64 * NB);
    const int tid = threadIdx.x;
    const int lane = tid & 63, wid = tid >> 6;
    const int wm = wid >> 1, wn = wid & 1;
    const int r16 = lane & 15, q = lane >> 4;
    v4f acc[NB][2][2];
#pragma unroll
    for (int b = 0; b < NB; b++)
#pragma unroll
        for (int i = 0; i < 2; i++)
#pragma unroll
            for (int j = 0; j < 2; j++) acc[b][i][j] = (v4f){0.f, 0.f, 0.f, 0.f};

    const int srow = tid >> 3;            // 0..31
    const int sc8  = tid & 7;             // 16B chunk in 64-elem row
    const int cbw  = (bn0 >> 4) + wn * 2;
    const int nK = (K + 63) >> 6;

    // prefetch registers (tile to be written next)
    v8s ph[2], pl[2];
    {
        int gk = sc8 * 8;
#pragma unroll
        for (int p = 0; p < 2; p++) {
            int row = p * 32 + srow;
            ph[p] = (v8s){0,0,0,0,0,0,0,0};
            pl[p] = (v8s){0,0,0,0,0,0,0,0};
            if (gk < K) {
                size_t go = (size_t)(bm + row) * ldA + gk;
                ph[p] = *(const v8s*)(const void*)(Ah + go);
                pl[p] = *(const v8s*)(const void*)(Al + go);
            }
        }
    }

    for (int s = 0; s < nK; s++) {
        const int k0 = s << 6;
        __syncthreads();   // all waves done reading previous tile
        // ---- write prefetched tile s ----
#pragma unroll
        for (int p = 0; p < 2; p++) {
            int row = p * 32 + srow;
            int bo = row * 128 + ((sc8 * 16) ^ ((row & 7) << 4));
            *(v8s*)(void*)((char*)AhS + bo) = ph[p];
            *(v8s*)(void*)((char*)AlS + bo) = pl[p];
        }
        __syncthreads();   // tile visible
        // ---- B fragment loads for tile s (ALL, before prefetch) ----
        v8s bfh[2][NB][2], bfl[2][NB][2];
#pragma unroll
        for (int kc = 0; kc < 2; kc++) {
            int kchunk = (k0 >> 5) + kc;
#pragma unroll
            for (int nb = 0; nb < NB; nb++)
#pragma unroll
                for (int nf = 0; nf < 2; nf++) {
                    int colblk = cbw + nb * 4 + nf;
                    size_t fo = ((size_t)(colblk * KC + kchunk) * 64 + lane) * 8;
                    bfh[kc][nb][nf] = *(const v8s*)(const void*)(Bh + fo);
                    bfl[kc][nb][nf] = *(const v8s*)(const void*)(Bl + fo);
                }
        }
        // ---- prefetch tile s+1 into regs (stays in flight through compute) ----
        if (s + 1 < nK) {
            int gk = (k0 + 64) + sc8 * 8;
#pragma unroll
            for (int p = 0; p < 2; p++) {
                int row = p * 32 + srow;
                v8s hv = (v8s){0,0,0,0,0,0,0,0};
                v8s lv = (v8s){0,0,0,0,0,0,0,0};
                if (gk < K) {
                    size_t go = (size_t)(bm + row) * ldA + gk;
                    hv = *(const v8s*)(const void*)(Ah + go);
                    lv = *(const v8s*)(const void*)(Al + go);
                }
                ph[p] = hv;
                pl[p] = lv;
            }
        }
        // ---- compute ----
#pragma unroll
        for (int kc = 0; kc < 2; kc++) {
#pragma unroll
            for (int mf = 0; mf < 2; mf++) {
                int arow = wm * 32 + mf * 16 + r16;
                int ao = arow * 128 + (((kc * 64) + q * 16) ^ ((arow & 7) << 4));
                v8s ah = *(const v8s*)(const void*)((const char*)AhS + ao);
                v8s al = *(const v8s*)(const void*)((const char*)AlS + ao);
#pragma unroll
                for (int nb = 0; nb < NB; nb++)
#pragma unroll
                    for (int nf = 0; nf < 2; nf++) {
                        acc[nb][mf][nf] = __builtin_amdgcn_mfma_f32_16x16x32_bf16(ah, bfh[kc][nb][nf], acc[nb][mf][nf], 0, 0, 0);
                        acc[nb][mf][nf] = __builtin_amdgcn_mfma_f32_16x16x32_bf16(al, bfh[kc][nb][nf], acc[nb][mf][nf], 0, 0, 0);
                        acc[nb][mf][nf] = __builtin_amdgcn_mfma_f32_16x16x32_bf16(ah, bfl[kc][nb][nf], acc[nb][mf][nf], 0, 0, 0);
                    }
            }
        }
    }
    // ---- epilogue ----
    float csum[NB][2], csq[NB][2];
#pragma unroll
    for (int nb = 0; nb < NB; nb++)
#pragma unroll
        for (int nf = 0; nf < 2; nf++) { csum[nb][nf] = 0.f; csq[nb][nf] = 0.f; }
#pragma unroll
    for (int nb = 0; nb < NB; nb++)
#pragma unroll
        for (int mf = 0; mf < 2; mf++)
#pragma unroll
            for (int nf = 0; nf < 2; nf++) {
                int col = bn0 + nb * 64 + wn * 32 + nf * 16 + r16;
                if (col < Ncol) {
                    float bv = bias ? bias[col] : 0.f;
#pragma unroll
                    for (int r = 0; r < 4; r++) {
                        int row = bm + wm * 32 + mf * 16 + q * 4 + r;
                        float v = acc[nb][mf][nf][r] + bv;
                        if (ACC) v += CfIn[(size_t)row * ldCin + col];
                        if (EPI == 1) v = fmaxf(v, 0.f);
                        if (EPI == 2) v = (v > 0.f) ? v : 0.01f * v;
                        if (STATS) { csum[nb][nf] += v; csq[nb][nf] = fmaf(v, v, csq[nb][nf]); }
                        size_t o = (size_t)row * ldC + col;
                        if (OUT == 0) {
                            Cf[o] = v;
                        } else {
                            us16 h = f2bf(v);
                            Ch[o] = h;
                            Cl[o] = f2bf(v - bf2f(h));
                        }
                    }
                }
            }
    if (STATS) {
        __syncthreads();
        float* sbs = (float*)AhS;   // per-(wm,wn,nb,nf,r16) 32-row sums
        float* sbq = (float*)AlS;
#pragma unroll
        for (int nb = 0; nb < NB; nb++)
#pragma unroll
            for (int nf = 0; nf < 2; nf++) {
                float s = csum[nb][nf];
                float t = csq[nb][nf];
                s += __shfl_down(s, 16, 64);
                s += __shfl_down(s, 32, 64);
                t += __shfl_down(t, 16, 64);
                t += __shfl_down(t, 32, 64);
                if (q == 0) {
                    int si = ((wm * 2 + wn) * NB + nb) * 32 + nf * 16 + r16;
                    sbs[si] = s;
                    sbq[si] = t;
                }
            }
        __syncthreads();
        if (wm == 0 && q == 0) {
            int rowblk = bm >> 6;
#pragma unroll
            for (int nb = 0; nb < NB; nb++)
#pragma unroll
                for (int nf = 0; nf < 2; nf++) {
                    int i0 = ((0 * 2 + wn) * NB + nb) * 32 + nf * 16 + r16;
                    int i1 = ((1 * 2 + wn) * NB + nb) * 32 + nf * 16 + r16;
                    int col = bn0 + nb * 64 + wn * 32 + nf * 16 + r16;
                    statsPart[(size_t)rowblk * statsStride + col] = sbs[i0] + sbs[i1];
                    statsPart[(size_t)(256 + rowblk) * statsStride + col] = sbq[i0] + sbq[i1];
                }
        }
    }
}

// ======================= fused fragment-order weight prep =======================
struct FrD {
    const float* W;
    us16* Bh;
    us16* Bl;
    int ldW, Kv, Nv, Na, KC, mode, cin, blk0;
};
struct FrPack { FrD d[16]; int nd; };

__global__ __launch_bounds__(256) void prep_fr_all(FrPack p)
{
    int b = blockIdx.x;
    int i = 0;
    for (int j = 1; j < p.nd; j++) if (b >= p.d[j].blk0) i = j;
    const FrD dd = p.d[i];
    int idx = (b - dd.blk0) * 256 + threadIdx.x;
    if (idx >= dd.Na * dd.KC * 32) return;
    int e = idx & 7, lane = (idx >> 3) & 63, rem = idx >> 9;
    int kchunk = rem % dd.KC, colblk = rem / dd.KC;
    int n = colblk * 16 + (lane & 15);
    int k = kchunk * 32 + (lane >> 4) * 8 + e;
    float v = 0.f;
    if (dd.mode == 0) {
        if (k < dd.Kv && n < dd.Nv) v = dd.W[(size_t)k * dd.ldW + n];
    } else if (dd.mode == 1) {
        int cin = dd.cin, cout = dd.Nv;
        if (n < cout && k < 3 * cin) {
            if (k < cin)          v = dd.W[(size_t)(cin + k) * cout + n] * 0.125f + dd.W[(size_t)(3 * cin + k) * cout + n];
            else if (k < 2 * cin) v = dd.W[(size_t)(2 * cin + (k - cin)) * cout + n];
            else                  v = dd.W[(size_t)(4 * cin + (k - 2 * cin)) * cout + n];
        }
    } // mode 2: zero
    us16 h = f2bf(v);
    dd.Bh[idx] = h;
    dd.Bl[idx] = f2bf(v - bf2f(h));
}

// fused Wx prep (BN-scaled, fragment order) + bias2 reduction
__global__ __launch_bounds__(256) void fusedwx_k(
    const float* __restrict__ Wx, const float* __restrict__ scale,
    const float* __restrict__ shift, const float* __restrict__ bx,
    us16* __restrict__ Bh, us16* __restrict__ Bl,
    int K, int N, int KC, int prepBlocks, float* __restrict__ bias2)
{
    if ((int)blockIdx.x < prepBlocks) {
        int idx = blockIdx.x * 256 + threadIdx.x;
        if (idx >= N * KC * 32) return;
        int e = idx & 7, lane = (idx >> 3) & 63, rem = idx >> 9;
        int kchunk = rem % KC, colblk = rem / KC;
        int n = colblk * 16 + (lane & 15);
        int k = kchunk * 32 + (lane >> 4) * 8 + e;
        float v = (k < K && n < N) ? Wx[(size_t)k * N + n] * scale[k] : 0.f;
        us16 h = f2bf(v);
        Bh[idx] = h;
        Bl[idx] = f2bf(v - bf2f(h));
    } else {
        int n = blockIdx.x - prepBlocks;
        int tid = threadIdx.x;
        float s = 0.f;
        for (int k = tid; k < K; k += 256) s = fmaf(shift[k], Wx[(size_t)k * N + n], s);
        __shared__ float red[256];
        red[tid] = s; __syncthreads();
        for (int st = 128; st > 0; st >>= 1) { if (tid < st) red[tid] += red[tid + st]; __syncthreads(); }
        if (tid == 0) bias2[n] = red[0] + bx[n];
    }
}

// W12 = W1@W2 in fragment order (K=256, N alloc 64 valid 32, KC=8)
__global__ void w12frag_k(const float* __restrict__ W1, const float* __restrict__ W2,
                          us16* __restrict__ Bh, us16* __restrict__ Bl)
{
    int idx = blockIdx.x * 256 + threadIdx.x;
    if (idx >= 64 * 8 * 32) return;
    int e = idx & 7, lane = (idx >> 3) & 63, rem = idx >> 9;
    int kchunk = rem % 8, colblk = rem / 8;
    int n = colblk * 16 + (lane & 15);
    int k = kchunk * 32 + (lane >> 4) * 8 + e;
    float v = 0.f;
    if (n < 32 && k < 256) {
        for (int j = 0; j < 64; j++) v = fmaf(W1[(size_t)k * 64 + j], W2[(size_t)j * 32 + n], v);
    }
    us16 h = f2bf(v);
    Bh[idx] = h;
    Bl[idx] = f2bf(v - bf2f(h));
}

// b12[n] = b2[n] + b1 @ W2[:,n]
__global__ void bias12_k(const float* __restrict__ b1, const float* __restrict__ W2,
                         const float* __restrict__ b2, float* __restrict__ b12)
{
    int n = threadIdx.x;
    if (n >= 32) return;
    float s = b2[n];
    for (int j = 0; j < 64; j++) s = fmaf(b1[j], W2[(size_t)j * 32 + n], s);
    b12[n] = s;
}

// concat bias for merged GEMM: [0]*cin ++ bm ++ bu
__global__ void prep_biasMU(const float* __restrict__ bm, const float* __restrict__ bu,
                            float* __restrict__ o, int cin, int cout)
{
    int i = blockIdx.x * 256 + threadIdx.x;
    if (i >= 2 * cin + cout) return;
    float v;
    if (i < cin)          v = 0.f;
    else if (i < 2 * cin) v = bm[i - cin];
    else                  v = bu[i - 2 * cin];
    o[i] = v;
}

// fused input splits: ns -> X1 (ld512 off0), dm -> dm planes (ld256)
__global__ void csplit2_k(const float* __restrict__ ns, us16* __restrict__ Xh, us16* __restrict__ Xl,
                          const float* __restrict__ dm, us16* __restrict__ Dh, us16* __restrict__ Dl)
{
    int b = blockIdx.x;
    if (b < 8192) {
        int idx = b * 256 + threadIdx.x;          // N*128
        int rrow = idx >> 7, c = idx & 127;
        float v = ns[idx];
        us16 h = f2bf(v);
        size_t o = (size_t)rrow * 512 + c;
        Xh[o] = h;
        Xl[o] = f2bf(v - bf2f(h));
    } else {
        int idx = (b - 8192) * 256 + threadIdx.x; // N*256
        float v = dm[idx];
        us16 h = f2bf(v);
        Dh[idx] = h;
        Dl[idx] = f2bf(v - bf2f(h));
    }
}

// f32 [16384, w] (ld ldS) -> split planes at column offset offX
__global__ void csplit_k(const float* __restrict__ src, int ldS, int w,
                         us16* __restrict__ Xh, us16* __restrict__ Xl,
                         int ldX, int offX)
{
    int idx = blockIdx.x * 256 + threadIdx.x;
    if (idx >= NNODE * w) return;
    int rrow = idx / w, c = idx - rrow * w;
    float v = src[(size_t)rrow * ldS + c];
    us16 h = f2bf(v);
    size_t o = (size_t)rrow * ldX + offX + c;
    Xh[o] = h;
    Xl[o] = f2bf(v - bf2f(h));
}

// ======================= PNA aggregation (split-bf16 output into X) =======================
__global__ __launch_bounds__(256)
void agg2_k(const float* __restrict__ H2, const float* __restrict__ es,
            const int* __restrict__ src, const float* __restrict__ Wme,
            us16* __restrict__ Xh, us16* __restrict__ Xl,
            int cin, int ldH, int ldX, int offX)
{
    const int g = blockIdx.x;
    const int c0 = blockIdx.y * 64;
    const int qz = blockIdx.z;
    const int tid = threadIdx.x;
    const int nl = tid >> 6, c = tid & 63;
    const int cc = c0 + c;
    const bool act = cc < cin;
    __shared__ float esl[4][128];
    __shared__ int srcl[512];
    {
        int e0 = g * 2048 + qz * 512;
        for (int i = tid; i < 512; i += 256) srcl[i] = src[e0 + i] - g * 256;
    }
    float wreg[16];
#pragma unroll
    for (int j = 0; j < 16; j++) wreg[j] = act ? Wme[j * cin + cc] : 0.f;
    __syncthreads();
    const float* Hsrc = H2 + (size_t)(g * 256) * ldH + c0;
    const float* Hdst = H2 + (size_t)(g * 256) * ldH + cin + c0;
    for (int i = 0; i < 16; i++) {
        const int vl = qz * 64 + i * 4 + nl;
        {
            const float* ep = es + (size_t)(g * 256 + vl) * 128;
            esl[nl][c] = ep[c];
            esl[nl][64 + c] = ep[64 + c];
        }
        __syncthreads();
        if (act) {
            float hd = Hdst[(size_t)vl * ldH + c];
            float sum = 0.f, sq = 0.f, mx = -INFINITY;
#pragma unroll
            for (int e = 0; e < 8; e++) {
                int sl = srcl[(i * 4 + nl) * 8 + e];
                float m = hd + Hsrc[(size_t)sl * ldH + c];
                float4 e0 = *(const float4*)&esl[nl][e * 16 + 0];
                float4 e1 = *(const float4*)&esl[nl][e * 16 + 4];
                float4 e2 = *(const float4*)&esl[nl][e * 16 + 8];
                float4 e3 = *(const float4*)&esl[nl][e * 16 + 12];
                m = fmaf(e0.x, wreg[0], m);  m = fmaf(e0.y, wreg[1], m);
                m = fmaf(e0.z, wreg[2], m);  m = fmaf(e0.w, wreg[3], m);
                m = fmaf(e1.x, wreg[4], m);  m = fmaf(e1.y, wreg[5], m);
                m = fmaf(e1.z, wreg[6], m);  m = fmaf(e1.w, wreg[7], m);
                m = fmaf(e2.x, wreg[8], m);  m = fmaf(e2.y, wreg[9], m);
                m = fmaf(e2.z, wreg[10], m); m = fmaf(e2.w, wreg[11], m);
                m = fmaf(e3.x, wreg[12], m); m = fmaf(e3.y, wreg[13], m);
                m = fmaf(e3.z, wreg[14], m); m = fmaf(e3.w, wreg[15], m);
                sum += m;
                sq = fmaf(m, m, sq);
                mx = fmaxf(mx, m);
            }
            float mean = sum * 0.125f, msq = sq * 0.125f;
            float stdv = sqrtf(fmaxf(msq - mean * mean, 0.f) + 1e-30f);
            size_t o = (size_t)(g * 256 + vl) * ldX + offX + cc;
            us16 h;
            h = f2bf(sum);  Xh[o] = h;            Xl[o] = f2bf(sum - bf2f(h));
            h = f2bf(mx);   Xh[o + cin] = h;      Xl[o + cin] = f2bf(mx - bf2f(h));
            h = f2bf(stdv); Xh[o + 2 * cin] = h;  Xl[o + 2 * cin] = f2bf(stdv - bf2f(h));
        }
        __syncthreads();
    }
}

// ======================= BatchNorm stats pass 2 =======================
__global__ void bnstats2_k(const float* __restrict__ part, const float* __restrict__ bng,
                           const float* __restrict__ bnb, float* __restrict__ scale,
                           float* __restrict__ shift, int cout)
{
    int c = threadIdx.x;
    if (c >= cout) return;
    float s = 0.f, q = 0.f;
    for (int b = 0; b < 256; b++) { s += part[(size_t)b * cout + c]; q += part[(size_t)(256 + b) * cout + c]; }
    float mean = s / 16384.f;
    float var  = q / 16384.f - mean * mean;
    float sc   = bng[c] / sqrtf(var + 1e-5f);
    scale[c] = sc;
    shift[c] = bnb[c] - mean * sc;
}

// ======================= head =======================
__global__ void rowmax_k(const float* __restrict__ h3, float* __restrict__ nm)
{
    int wave = threadIdx.x >> 6;
    int lane = threadIdx.x & 63;
    int node = blockIdx.x * 4 + wave;
    const float* row = h3 + (size_t)node * 192;
    float m = -INFINITY;
    for (int t = lane; t < 192; t += 64) m = fmaxf(m, row[t]);
#pragma unroll
    for (int off = 32; off > 0; off >>= 1) m = fmaxf(m, __shfl_down(m, off, 64));
    if (lane == 0) nm[node] = m;
}

__global__ __launch_bounds__(256) void g_k(const float* __restrict__ nm,
    const float* __restrict__ W3, const float* __restrict__ b3,
    const float* __restrict__ W4, const float* __restrict__ b4,
    float* __restrict__ g)
{
    __shared__ float row[256];
    __shared__ float t1[64];
    int b = blockIdx.x, tid = threadIdx.x;
    row[tid] = nm[b * 256 + tid];
    __syncthreads();
    if (tid < 64) {
        float a = b3[tid];
        for (int k = 0; k < 256; k++) a = fmaf(row[k], W3[k * 64 + tid], a);
        t1[tid] = fmaxf(a, 0.f);
    }
    __syncthreads();
    float a = b4[tid];
    for (int j = 0; j < 64; j++) a = fmaf(t1[j], W4[j * 256 + tid], a);
    g[b * 256 + tid] = 1.f / (1.f + expf(-a));
}

// ======================= masked softmax (parallel, 2-pass; sm1 caches logits in out) ====
__global__ __launch_bounds__(256) void sm1_k(const float* __restrict__ mask,
    const float* __restrict__ g, const float* __restrict__ h3, float* __restrict__ part,
    float* __restrict__ out)
{
    int b = blockIdx.x, s = blockIdx.y, tid = threadIdx.x;
    float l[24];
#pragma unroll
    for (int t = 0; t < 24; t++) {
        int i = s * 6144 + t * 256 + tid;
        size_t idx = (size_t)b * 49152 + i;
        float mk = mask[idx];
        l[t] = (mk == 0.f) ? -1e5f : g[b * 256 + i / 192] * h3[idx];
        out[idx] = l[t];
    }
    float m = -INFINITY;
#pragma unroll
    for (int t = 0; t < 24; t++) m = fmaxf(m, l[t]);
    __shared__ float red[256];
    red[tid] = m; __syncthreads();
    for (int st = 128; st > 0; st >>= 1) { if (tid < st) red[tid] = fmaxf(red[tid], red[tid + st]); __syncthreads(); }
    m = red[0]; __syncthreads();
    float z = 0.f;
#pragma unroll
    for (int t = 0; t < 24; t++) z += expf(l[t] - m);
    red[tid] = z; __syncthreads();
    for (int st = 128; st > 0; st >>= 1) { if (tid < st) red[tid] += red[tid + st]; __syncthreads(); }
    if (tid == 0) { part[(b * 8 + s) * 2] = m; part[(b * 8 + s) * 2 + 1] = red[0]; }
}

__global__ void sm2_k(const float* __restrict__ part, float* __restrict__ mz)
{
    int b = threadIdx.x;
    if (b >= 64) return;
    float M = -INFINITY;
    for (int s = 0; s < 8; s++) M = fmaxf(M, part[(b * 8 + s) * 2]);
    float Z = 0.f;
    for (int s = 0; s < 8; s++) Z += part[(b * 8 + s) * 2 + 1] * expf(part[(b * 8 + s) * 2] - M);
    mz[b * 2] = M;
    mz[b * 2 + 1] = 1.f / Z;
}

__global__ __launch_bounds__(256) void sm3_k(const float* __restrict__ mz,
    float* __restrict__ out)
{
    int b = blockIdx.x, s = blockIdx.y, tid = threadIdx.x;
    float M = mz[b * 2], invZ = mz[b * 2 + 1];
#pragma unroll
    for (int t = 0; t < 24; t++) {
        int i = s * 6144 + t * 256 + tid;
        size_t idx = (size_t)b * 49152 + i;
        float v = out[idx];
        out[idx] = expf(v - M) * invZ;
    }
}

// ======================= launcher =======================
extern "C" void kernel_launch(void* const* d_in, const int* in_sizes, int n_in,
                              void* d_out, int out_size, void* d_ws, size_t ws_size,
                              hipStream_t stream)
{
    const float* ns   = (const float*)d_in[0];
    const float* es   = (const float*)d_in[1];
    const float* dm   = (const float*)d_in[2];
    const float* mask = (const float*)d_in[3];
    const int*   src  = (const int*)d_in[4];
    const float* Wm1 = (const float*)d_in[6],  *bm1 = (const float*)d_in[7];
    const float* Wu1 = (const float*)d_in[8],  *bu1 = (const float*)d_in[9];
    const float* bng1= (const float*)d_in[10], *bnb1= (const float*)d_in[11];
    const float* Wx1 = (const float*)d_in[12], *bx1 = (const float*)d_in[13];
    const float* Wm2 = (const float*)d_in[14], *bm2 = (const float*)d_in[15];
    const float* Wu2 = (const float*)d_in[16], *bu2 = (const float*)d_in[17];
    const float* bng2= (const float*)d_in[18], *bnb2= (const float*)d_in[19];
    const float* Wx2 = (const float*)d_in[20], *bx2 = (const float*)d_in[21];
    const float* Wm3 = (const float*)d_in[22], *bm3 = (const float*)d_in[23];
    const float* Wu3 = (const float*)d_in[24], *bu3 = (const float*)d_in[25];
    const float* bng3= (const float*)d_in[26], *bnb3= (const float*)d_in[27];
    const float* Wx3 = (const float*)d_in[28], *bx3 = (const float*)d_in[29];
    const float* W1 = (const float*)d_in[30], *b1 = (const float*)d_in[31];
    const float* W2 = (const float*)d_in[32], *b2 = (const float*)d_in[33];
    const float* W3 = (const float*)d_in[34], *b3 = (const float*)d_in[35];
    const float* W4 = (const float*)d_in[36], *b4 = (const float*)d_in[37];
    float* out = (float*)d_out;

    const int N = NNODE;
    char* base = (char*)d_ws;
    size_t off = 0;
    auto alloc = [&](size_t bytes) -> void* {
        void* p = base + off;
        off = (off + bytes + 255) & ~(size_t)255;
        return p;
    };
    us16* Xh = (us16*)alloc((size_t)N * 1728 * 2);
    us16* Xl = (us16*)alloc((size_t)N * 1728 * 2);
    float* H2   = (float*)alloc((size_t)N * 1216 * 4);   // [Hsrc|Hdst|u_partial]
    us16* uh = (us16*)alloc((size_t)N * 384 * 2);
    us16* ul = (us16*)alloc((size_t)N * 384 * 2);
    us16* dmh = (us16*)alloc((size_t)N * 256 * 2);
    us16* dml = (us16*)alloc((size_t)N * 256 * 2);
    float* h3b  = (float*)alloc((size_t)N * 192 * 4);
    float* d2f  = (float*)alloc((size_t)N * 32 * 4);
    float* part = (float*)alloc((size_t)512 * 384 * 4);
    float* scale= (float*)alloc(384 * 4);
    float* shift= (float*)alloc(384 * 4);
    float* bias2= (float*)alloc(384 * 4);
    float* b12  = (float*)alloc(32 * 4);
    float* biasMU1 = (float*)alloc(640 * 4);
    float* biasMU2 = (float*)alloc(1216 * 4);
    float* biasMU3 = (float*)alloc(960 * 4);
    float* nm   = (float*)alloc((size_t)N * 4);
    float* gbuf = (float*)alloc((size_t)N * 4);
    float* smp  = (float*)alloc(64 * 8 * 2 * 4);
    float* smz  = (float*)alloc(64 * 2 * 4);
    auto aw = [&](size_t elems) -> us16* { return (us16*)alloc(elems * 2); };
    us16 *BM1h = aw((size_t)640 * 4 * 32),    *BM1l = aw((size_t)640 * 4 * 32);
    us16 *BA1h = aw((size_t)384 * 12 * 32),   *BA1l = aw((size_t)384 * 12 * 32);
    us16 *BX1h = aw((size_t)384 * 12 * 32),   *BX1l = aw((size_t)384 * 12 * 32);
    us16 *BM2h = aw((size_t)1280 * 14 * 32),  *BM2l = aw((size_t)1280 * 14 * 32);
    us16 *BA2h = aw((size_t)384 * 40 * 32),   *BA2l = aw((size_t)384 * 40 * 32);
    us16 *BX2h = aw((size_t)384 * 12 * 32),   *BX2l = aw((size_t)384 * 12 * 32);
    us16 *BM3h = aw((size_t)1024 * 12 * 32),  *BM3l = aw((size_t)1024 * 12 * 32);
    us16 *BA3h = aw((size_t)192 * 36 * 32),   *BA3l = aw((size_t)192 * 36 * 32);
    us16 *BX3h = aw((size_t)192 * 6 * 32),    *BX3l = aw((size_t)192 * 6 * 32);
    us16 *B12h = aw((size_t)64 * 8 * 32),     *B12l = aw((size_t)64 * 8 * 32);

    auto gp = [](size_t n) { return dim3((unsigned)((n + 255) / 256)); };
    auto fsec = [](us16* b, int c0, int KC) { return b + (size_t)(c0 / 16) * KC * 512; };

    // ---- fused fragment prep descriptors ----
    FrPack pk;
    int nd = 0, blk = 0;
    auto addD = [&](const float* W, us16* Bh, us16* Bl, int ldW, int Kv, int Nv, int Na, int KC, int mode, int cin) {
        pk.d[nd] = {W, Bh, Bl, ldW, Kv, Nv, Na, KC, mode, cin, blk};
        blk += (Na * KC * 32 + 255) / 256;
        nd++;
    };
    addD(Wm1,             fsec(BM1h,0,4),    fsec(BM1l,0,4),    128, 128, 128, 128, 4, 0, 0);
    addD(Wm1 + 128*128,   fsec(BM1h,128,4),  fsec(BM1l,128,4),  128, 128, 128, 128, 4, 0, 0);
    addD(Wu1,             fsec(BM1h,256,4),  fsec(BM1l,256,4),  384, 128, 384, 384, 4, 0, 0);
    addD(Wu1,             BA1h, BA1l,        0,   0,   384, 384, 12, 1, 128);
    addD(Wm2,             fsec(BM2h,0,14),   fsec(BM2l,0,14),   416, 416, 416, 416, 14, 0, 0);
    addD(Wm2 + 416*416,   fsec(BM2h,416,14), fsec(BM2l,416,14), 416, 416, 416, 416, 14, 0, 0);
    addD(Wu2,             fsec(BM2h,832,14), fsec(BM2l,832,14), 384, 416, 384, 384, 14, 0, 0);
    addD(nullptr,         fsec(BM2h,1216,14),fsec(BM2l,1216,14),0,   0,   0,   64,  14, 2, 0);
    addD(Wu2,             BA2h, BA2l,        0,   0,   384, 384, 40, 1, 416);
    addD(Wm3,             fsec(BM3h,0,12),   fsec(BM3l,0,12),   384, 384, 384, 384, 12, 0, 0);
    addD(Wm3 + 384*384,   fsec(BM3h,384,12), fsec(BM3l,384,12), 384, 384, 384, 384, 12, 0, 0);
    addD(Wu3,             fsec(BM3h,768,12), fsec(BM3l,768,12), 192, 384, 192, 192, 12, 0, 0);
    addD(nullptr,         fsec(BM3h,960,12), fsec(BM3l,960,12), 0,   0,   0,   64,  12, 2, 0);
    addD(Wu3,             BA3h, BA3l,        0,   0,   192, 192, 36, 1, 384);
    pk.nd = nd;

    // ---- input splits + preps ----
    csplit2_k<<<8192 + 16384, 256, 0, stream>>>(ns, Xh, Xl, dm, dmh, dml);
    prep_fr_all<<<blk, 256, 0, stream>>>(pk);
    w12frag_k<<<gp(64 * 8 * 32), 256, 0, stream>>>(W1, W2, B12h, B12l);
    bias12_k<<<1, 32, 0, stream>>>(b1, W2, b2, b12);
    prep_biasMU<<<gp(640), 256, 0, stream>>>(bm1, bu1, biasMU1, 128, 384);
    prep_biasMU<<<gp(1216), 256, 0, stream>>>(bm2, bu2, biasMU2, 416, 384);
    prep_biasMU<<<gp(960), 256, 0, stream>>>(bm3, bu3, biasMU3, 384, 192);

    // ---- d2 = dm @ W12 + b12 ----
    mgemm9<0, 0, 0, 1, 0><<<256, 256, 0, stream>>>(1, dmh, dml, 256, 256, B12h, B12l, 8,
        nullptr, 0, d2f, nullptr, nullptr, 32, 32, b12, nullptr, 0);

    // ================= layer 1 (cin=128, X ld 512, H2 ld 640) =================
    mgemm9<0, 0, 0, 2, 0><<<256 * 5, 256, 0, stream>>>(5, Xh, Xl, 512, 128, BM1h, BM1l, 4,
        nullptr, 0, H2, nullptr, nullptr, 640, 640, biasMU1, nullptr, 0);
    agg2_k<<<dim3(64, 2, 4), 256, 0, stream>>>(H2, es, src, Wm1 + 2 * 128 * 128, Xh, Xl, 128, 640, 512, 128);
    mgemm9<0, 1, 1, 2, 1><<<256 * 3, 256, 0, stream>>>(3, Xh + 128, Xl + 128, 512, 384, BA1h, BA1l, 12,
        H2 + 256, 640, nullptr, uh, ul, 384, 384, nullptr, part, 384);
    bnstats2_k<<<1, 384, 0, stream>>>(part, bng1, bnb1, scale, shift, 384);
    fusedwx_k<<<576 + 384, 256, 0, stream>>>(Wx1, scale, shift, bx1, BX1h, BX1l, 384, 384, 12, 576, bias2);
    mgemm9<1, 1, 0, 2, 0><<<256 * 3, 256, 0, stream>>>(3, uh, ul, 384, 384, BX1h, BX1l, 12,
        nullptr, 0, nullptr, Xh, Xl, 1728, 384, bias2, nullptr, 0);   // h2a -> X2[0:384)
    csplit_k<<<gp((size_t)N * 32), 256, 0, stream>>>(d2f, 32, 32, Xh, Xl, 1728, 384);  // d2 -> X2[384:416)

    // ================= layer 2 (cin=416, X ld 1728, H2 ld 1216) =================
    mgemm9<0, 0, 0, 2, 0><<<256 * 10, 256, 0, stream>>>(10, Xh, Xl, 1728, 416, BM2h, BM2l, 14,
        nullptr, 0, H2, nullptr, nullptr, 1216, 1216, biasMU2, nullptr, 0);
    agg2_k<<<dim3(64, 7, 4), 256, 0, stream>>>(H2, es, src, Wm2 + 2 * 416 * 416, Xh, Xl, 416, 1216, 1728, 416);
    mgemm9<0, 1, 1, 2, 1><<<256 * 3, 256, 0, stream>>>(3, Xh + 416, Xl + 416, 1728, 1248, BA2h, BA2l, 40,
        H2 + 832, 1216, nullptr, uh, ul, 384, 384, nullptr, part, 384);
    bnstats2_k<<<1, 384, 0, stream>>>(part, bng2, bnb2, scale, shift, 384);
    fusedwx_k<<<576 + 384, 256, 0, stream>>>(Wx2, scale, shift, bx2, BX2h, BX2l, 384, 384, 12, 576, bias2);
    mgemm9<1, 1, 0, 2, 0><<<256 * 3, 256, 0, stream>>>(3, uh, ul, 384, 384, BX2h, BX2l, 12,
        nullptr, 0, nullptr, Xh, Xl, 1536, 384, bias2, nullptr, 0);   // h3-in -> X3[0:384)

    // ================= layer 3 (cin=384, X ld 1536, H2 ld 960) =================
    mgemm9<0, 0, 0, 2, 0><<<256 * 8, 256, 0, stream>>>(8, Xh, Xl, 1536, 384, BM3h, BM3l, 12,
        nullptr, 0, H2, nullptr, nullptr, 960, 960, biasMU3, nullptr, 0);
    agg2_k<<<dim3(64, 6, 4), 256, 0, stream>>>(H2, es, src, Wm3 + 2 * 384 * 384, Xh, Xl, 384, 960, 1536, 384);
    mgemm9<0, 1, 1, 1, 1><<<256 * 3, 256, 0, stream>>>(3, Xh + 384, Xl + 384, 1536, 1152, BA3h, BA3l, 36,
        H2 + 768, 960, nullptr, uh, ul, 192, 192, nullptr, part, 192);
    bnstats2_k<<<1, 384, 0, stream>>>(part, bng3, bnb3, scale, shift, 192);
    fusedwx_k<<<144 + 192, 256, 0, stream>>>(Wx3, scale, shift, bx3, BX3h, BX3l, 192, 192, 6, 144, bias2);
    mgemm9<2, 0, 0, 1, 0><<<256 * 3, 256, 0, stream>>>(3, uh, ul, 192, 192, BX3h, BX3l, 6,
        nullptr, 0, h3b, nullptr, nullptr, 192, 192, bias2, nullptr, 0);

    // ---- head ----
    rowmax_k<<<N / 4, 256, 0, stream>>>(h3b, nm);
    g_k<<<64, 256, 0, stream>>>(nm, W3, b3, W4, b4, gbuf);
    sm1_k<<<dim3(64, 8), 256, 0, stream>>>(mask, gbuf, h3b, smp, out);
    sm2_k<<<1, 64, 0, stream>>>(smp, smz);
    sm3_k<<<dim3(64, 8), 256, 0, stream>>>(smz, out);
}

// Round 14
// 619.323 us; speedup vs baseline: 1.2597x; 1.2597x over previous
//
#include <hip/hip_runtime.h>
#include <hip/hip_bf16.h>

#define NNODE 16384

typedef short v8s __attribute__((ext_vector_type(8)));
typedef float v4f __attribute__((ext_vector_type(4)));
typedef unsigned short us16;

__device__ __forceinline__ us16 f2bf(float v) {
    unsigned u = __float_as_uint(v);
    unsigned r = (u + 0x7FFF + ((u >> 16) & 1)) >> 16;
    return (us16)r;
}
__device__ __forceinline__ float bf2f(us16 s) {
    return __uint_as_float(((unsigned)s) << 16);
}

// ======================= split-bf16 MFMA GEMM v9 =======================
// A in LDS (hi/lo, XOR swizzle), BM=64, NB col-groups of 64, 4 waves (2x2).
// Reg-prefetch pipeline; B in MFMA fragment order (coalesced per-wave loads).
// XCD-chunked 1-D grid swizzle (nwg%8==0). Optional fused BN-stats (STATS=1).
// NOTE: launch_bounds (256,3) — (256,4) forces reg cap 128 (VGPR+AGPR unified)
// and SPILLS (~140MB scratch traffic/dispatch, round-13 regression).
// 3-term split: AhBh + AlBh + AhBl. ACC: += f32 CfIn. OUT: 0=f32, 1=split bf16.
template<int EPI, int OUT, int ACC, int NB, int STATS>
__global__ __launch_bounds__(256, 3)
void mgemm9(int nyPanels,
            const us16* __restrict__ Ah, const us16* __restrict__ Al,
            int ldA, int K,
            const us16* __restrict__ Bh, const us16* __restrict__ Bl, int KC,
            const float* __restrict__ CfIn, int ldCin,
            float* __restrict__ Cf, us16* __restrict__ Ch, us16* __restrict__ Cl,
            int ldC, int Ncol, const float* __restrict__ bias,
            float* __restrict__ statsPart, int statsStride)
{
    __shared__ __align__(16) us16 AhS[64 * 64];
    __shared__ __align__(16) us16 AlS[64 * 64];
    const int nwg = gridDim.x;
    const int bid = blockIdx.x;
    const int wgid = (bid & 7) * (nwg >> 3) + (bid >> 3);   // XCD-chunked (nwg%8==0)
    const int bm  = (wgid / nyPanels) * 64;
    const int bn0 = (wgid % nyPanels) * (64 * NB);
    const int tid = threadIdx.x;
    const int lane = tid & 63, wid = tid >> 6;
    const int wm = wid >> 1, wn = wid & 1;
    const int r16 = lane & 15, q = lane >> 4;
    v4f acc[NB][2][2];
#pragma unroll
    for (int b = 0; b < NB; b++)
#pragma unroll
        for (int i = 0; i < 2; i++)
#pragma unroll
            for (int j = 0; j < 2; j++) acc[b][i][j] = (v4f){0.f, 0.f, 0.f, 0.f};

    const int srow = tid >> 3;            // 0..31
    const int sc8  = tid & 7;             // 16B chunk in 64-elem row
    const int cbw  = (bn0 >> 4) + wn * 2;
    const int nK = (K + 63) >> 6;

    // prefetch registers (tile to be written next)
    v8s ph[2], pl[2];
    {
        int gk = sc8 * 8;
#pragma unroll
        for (int p = 0; p < 2; p++) {
            int row = p * 32 + srow;
            ph[p] = (v8s){0,0,0,0,0,0,0,0};
            pl[p] = (v8s){0,0,0,0,0,0,0,0};
            if (gk < K) {
                size_t go = (size_t)(bm + row) * ldA + gk;
                ph[p] = *(const v8s*)(const void*)(Ah + go);
                pl[p] = *(const v8s*)(const void*)(Al + go);
            }
        }
    }

    for (int s = 0; s < nK; s++) {
        const int k0 = s << 6;
        __syncthreads();   // all waves done reading previous tile
        // ---- write prefetched tile s ----
#pragma unroll
        for (int p = 0; p < 2; p++) {
            int row = p * 32 + srow;
            int bo = row * 128 + ((sc8 * 16) ^ ((row & 7) << 4));
            *(v8s*)(void*)((char*)AhS + bo) = ph[p];
            *(v8s*)(void*)((char*)AlS + bo) = pl[p];
        }
        __syncthreads();   // tile visible
        // ---- B fragment loads for tile s (ALL, before prefetch) ----
        v8s bfh[2][NB][2], bfl[2][NB][2];
#pragma unroll
        for (int kc = 0; kc < 2; kc++) {
            int kchunk = (k0 >> 5) + kc;
#pragma unroll
            for (int nb = 0; nb < NB; nb++)
#pragma unroll
                for (int nf = 0; nf < 2; nf++) {
                    int colblk = cbw + nb * 4 + nf;
                    size_t fo = ((size_t)(colblk * KC + kchunk) * 64 + lane) * 8;
                    bfh[kc][nb][nf] = *(const v8s*)(const void*)(Bh + fo);
                    bfl[kc][nb][nf] = *(const v8s*)(const void*)(Bl + fo);
                }
        }
        // ---- prefetch tile s+1 into regs (stays in flight through compute) ----
        if (s + 1 < nK) {
            int gk = (k0 + 64) + sc8 * 8;
#pragma unroll
            for (int p = 0; p < 2; p++) {
                int row = p * 32 + srow;
                v8s hv = (v8s){0,0,0,0,0,0,0,0};
                v8s lv = (v8s){0,0,0,0,0,0,0,0};
                if (gk < K) {
                    size_t go = (size_t)(bm + row) * ldA + gk;
                    hv = *(const v8s*)(const void*)(Ah + go);
                    lv = *(const v8s*)(const void*)(Al + go);
                }
                ph[p] = hv;
                pl[p] = lv;
            }
        }
        // ---- compute ----
#pragma unroll
        for (int kc = 0; kc < 2; kc++) {
#pragma unroll
            for (int mf = 0; mf < 2; mf++) {
                int arow = wm * 32 + mf * 16 + r16;
                int ao = arow * 128 + (((kc * 64) + q * 16) ^ ((arow & 7) << 4));
                v8s ah = *(const v8s*)(const void*)((const char*)AhS + ao);
                v8s al = *(const v8s*)(const void*)((const char*)AlS + ao);
#pragma unroll
                for (int nb = 0; nb < NB; nb++)
#pragma unroll
                    for (int nf = 0; nf < 2; nf++) {
                        acc[nb][mf][nf] = __builtin_amdgcn_mfma_f32_16x16x32_bf16(ah, bfh[kc][nb][nf], acc[nb][mf][nf], 0, 0, 0);
                        acc[nb][mf][nf] = __builtin_amdgcn_mfma_f32_16x16x32_bf16(al, bfh[kc][nb][nf], acc[nb][mf][nf], 0, 0, 0);
                        acc[nb][mf][nf] = __builtin_amdgcn_mfma_f32_16x16x32_bf16(ah, bfl[kc][nb][nf], acc[nb][mf][nf], 0, 0, 0);
                    }
            }
        }
    }
    // ---- epilogue ----
    float csum[NB][2], csq[NB][2];
#pragma unroll
    for (int nb = 0; nb < NB; nb++)
#pragma unroll
        for (int nf = 0; nf < 2; nf++) { csum[nb][nf] = 0.f; csq[nb][nf] = 0.f; }
#pragma unroll
    for (int nb = 0; nb < NB; nb++)
#pragma unroll
        for (int mf = 0; mf < 2; mf++)
#pragma unroll
            for (int nf = 0; nf < 2; nf++) {
                int col = bn0 + nb * 64 + wn * 32 + nf * 16 + r16;
                if (col < Ncol) {
                    float bv = bias ? bias[col] : 0.f;
#pragma unroll
                    for (int r = 0; r < 4; r++) {
                        int row = bm + wm * 32 + mf * 16 + q * 4 + r;
                        float v = acc[nb][mf][nf][r] + bv;
                        if (ACC) v += CfIn[(size_t)row * ldCin + col];
                        if (EPI == 1) v = fmaxf(v, 0.f);
                        if (EPI == 2) v = (v > 0.f) ? v : 0.01f * v;
                        if (STATS) { csum[nb][nf] += v; csq[nb][nf] = fmaf(v, v, csq[nb][nf]); }
                        size_t o = (size_t)row * ldC + col;
                        if (OUT == 0) {
                            Cf[o] = v;
                        } else {
                            us16 h = f2bf(v);
                            Ch[o] = h;
                            Cl[o] = f2bf(v - bf2f(h));
                        }
                    }
                }
            }
    if (STATS) {
        __syncthreads();
        float* sbs = (float*)AhS;   // per-(wm,wn,nb,nf,r16) 32-row sums
        float* sbq = (float*)AlS;
#pragma unroll
        for (int nb = 0; nb < NB; nb++)
#pragma unroll
            for (int nf = 0; nf < 2; nf++) {
                float s = csum[nb][nf];
                float t = csq[nb][nf];
                s += __shfl_down(s, 16, 64);
                s += __shfl_down(s, 32, 64);
                t += __shfl_down(t, 16, 64);
                t += __shfl_down(t, 32, 64);
                if (q == 0) {
                    int si = ((wm * 2 + wn) * NB + nb) * 32 + nf * 16 + r16;
                    sbs[si] = s;
                    sbq[si] = t;
                }
            }
        __syncthreads();
        if (wm == 0 && q == 0) {
            int rowblk = bm >> 6;
#pragma unroll
            for (int nb = 0; nb < NB; nb++)
#pragma unroll
                for (int nf = 0; nf < 2; nf++) {
                    int i0 = ((0 * 2 + wn) * NB + nb) * 32 + nf * 16 + r16;
                    int i1 = ((1 * 2 + wn) * NB + nb) * 32 + nf * 16 + r16;
                    int col = bn0 + nb * 64 + wn * 32 + nf * 16 + r16;
                    statsPart[(size_t)rowblk * statsStride + col] = sbs[i0] + sbs[i1];
                    statsPart[(size_t)(256 + rowblk) * statsStride + col] = sbq[i0] + sbq[i1];
                }
        }
    }
}

// ======================= fused fragment-order weight prep =======================
struct FrD {
    const float* W;
    us16* Bh;
    us16* Bl;
    int ldW, Kv, Nv, Na, KC, mode, cin, blk0;
};
struct FrPack { FrD d[16]; int nd; };

__global__ __launch_bounds__(256) void prep_fr_all(FrPack p)
{
    int b = blockIdx.x;
    int i = 0;
    for (int j = 1; j < p.nd; j++) if (b >= p.d[j].blk0) i = j;
    const FrD dd = p.d[i];
    int idx = (b - dd.blk0) * 256 + threadIdx.x;
    if (idx >= dd.Na * dd.KC * 32) return;
    int e = idx & 7, lane = (idx >> 3) & 63, rem = idx >> 9;
    int kchunk = rem % dd.KC, colblk = rem / dd.KC;
    int n = colblk * 16 + (lane & 15);
    int k = kchunk * 32 + (lane >> 4) * 8 + e;
    float v = 0.f;
    if (dd.mode == 0) {
        if (k < dd.Kv && n < dd.Nv) v = dd.W[(size_t)k * dd.ldW + n];
    } else if (dd.mode == 1) {
        int cin = dd.cin, cout = dd.Nv;
        if (n < cout && k < 3 * cin) {
            if (k < cin)          v = dd.W[(size_t)(cin + k) * cout + n] * 0.125f + dd.W[(size_t)(3 * cin + k) * cout + n];
            else if (k < 2 * cin) v = dd.W[(size_t)(2 * cin + (k - cin)) * cout + n];
            else                  v = dd.W[(size_t)(4 * cin + (k - 2 * cin)) * cout + n];
        }
    } // mode 2: zero
    us16 h = f2bf(v);
    dd.Bh[idx] = h;
    dd.Bl[idx] = f2bf(v - bf2f(h));
}

// fused Wx prep (BN-scaled, fragment order) + bias2 reduction
__global__ __launch_bounds__(256) void fusedwx_k(
    const float* __restrict__ Wx, const float* __restrict__ scale,
    const float* __restrict__ shift, const float* __restrict__ bx,
    us16* __restrict__ Bh, us16* __restrict__ Bl,
    int K, int N, int KC, int prepBlocks, float* __restrict__ bias2)
{
    if ((int)blockIdx.x < prepBlocks) {
        int idx = blockIdx.x * 256 + threadIdx.x;
        if (idx >= N * KC * 32) return;
        int e = idx & 7, lane = (idx >> 3) & 63, rem = idx >> 9;
        int kchunk = rem % KC, colblk = rem / KC;
        int n = colblk * 16 + (lane & 15);
        int k = kchunk * 32 + (lane >> 4) * 8 + e;
        float v = (k < K && n < N) ? Wx[(size_t)k * N + n] * scale[k] : 0.f;
        us16 h = f2bf(v);
        Bh[idx] = h;
        Bl[idx] = f2bf(v - bf2f(h));
    } else {
        int n = blockIdx.x - prepBlocks;
        int tid = threadIdx.x;
        float s = 0.f;
        for (int k = tid; k < K; k += 256) s = fmaf(shift[k], Wx[(size_t)k * N + n], s);
        __shared__ float red[256];
        red[tid] = s; __syncthreads();
        for (int st = 128; st > 0; st >>= 1) { if (tid < st) red[tid] += red[tid + st]; __syncthreads(); }
        if (tid == 0) bias2[n] = red[0] + bx[n];
    }
}

// W12 = W1@W2 in fragment order (K=256, N alloc 64 valid 32, KC=8)
__global__ void w12frag_k(const float* __restrict__ W1, const float* __restrict__ W2,
                          us16* __restrict__ Bh, us16* __restrict__ Bl)
{
    int idx = blockIdx.x * 256 + threadIdx.x;
    if (idx >= 64 * 8 * 32) return;
    int e = idx & 7, lane = (idx >> 3) & 63, rem = idx >> 9;
    int kchunk = rem % 8, colblk = rem / 8;
    int n = colblk * 16 + (lane & 15);
    int k = kchunk * 32 + (lane >> 4) * 8 + e;
    float v = 0.f;
    if (n < 32 && k < 256) {
        for (int j = 0; j < 64; j++) v = fmaf(W1[(size_t)k * 64 + j], W2[(size_t)j * 32 + n], v);
    }
    us16 h = f2bf(v);
    Bh[idx] = h;
    Bl[idx] = f2bf(v - bf2f(h));
}

// b12[n] = b2[n] + b1 @ W2[:,n]
__global__ void bias12_k(const float* __restrict__ b1, const float* __restrict__ W2,
                         const float* __restrict__ b2, float* __restrict__ b12)
{
    int n = threadIdx.x;
    if (n >= 32) return;
    float s = b2[n];
    for (int j = 0; j < 64; j++) s = fmaf(b1[j], W2[(size_t)j * 32 + n], s);
    b12[n] = s;
}

// concat bias for merged GEMM: [0]*cin ++ bm ++ bu
__global__ void prep_biasMU(const float* __restrict__ bm, const float* __restrict__ bu,
                            float* __restrict__ o, int cin, int cout)
{
    int i = blockIdx.x * 256 + threadIdx.x;
    if (i >= 2 * cin + cout) return;
    float v;
    if (i < cin)          v = 0.f;
    else if (i < 2 * cin) v = bm[i - cin];
    else                  v = bu[i - 2 * cin];
    o[i] = v;
}

// fused input splits: ns -> X1 (ld512 off0), dm -> dm planes (ld256)
__global__ void csplit2_k(const float* __restrict__ ns, us16* __restrict__ Xh, us16* __restrict__ Xl,
                          const float* __restrict__ dm, us16* __restrict__ Dh, us16* __restrict__ Dl)
{
    int b = blockIdx.x;
    if (b < 8192) {
        int idx = b * 256 + threadIdx.x;          // N*128
        int rrow = idx >> 7, c = idx & 127;
        float v = ns[idx];
        us16 h = f2bf(v);
        size_t o = (size_t)rrow * 512 + c;
        Xh[o] = h;
        Xl[o] = f2bf(v - bf2f(h));
    } else {
        int idx = (b - 8192) * 256 + threadIdx.x; // N*256
        float v = dm[idx];
        us16 h = f2bf(v);
        Dh[idx] = h;
        Dl[idx] = f2bf(v - bf2f(h));
    }
}

// f32 [16384, w] (ld ldS) -> split planes at column offset offX
__global__ void csplit_k(const float* __restrict__ src, int ldS, int w,
                         us16* __restrict__ Xh, us16* __restrict__ Xl,
                         int ldX, int offX)
{
    int idx = blockIdx.x * 256 + threadIdx.x;
    if (idx >= NNODE * w) return;
    int rrow = idx / w, c = idx - rrow * w;
    float v = src[(size_t)rrow * ldS + c];
    us16 h = f2bf(v);
    size_t o = (size_t)rrow * ldX + offX + c;
    Xh[o] = h;
    Xl[o] = f2bf(v - bf2f(h));
}

// ======================= PNA aggregation (split-bf16 output into X) =======================
__global__ __launch_bounds__(256)
void agg2_k(const float* __restrict__ H2, const float* __restrict__ es,
            const int* __restrict__ src, const float* __restrict__ Wme,
            us16* __restrict__ Xh, us16* __restrict__ Xl,
            int cin, int ldH, int ldX, int offX)
{
    const int g = blockIdx.x;
    const int c0 = blockIdx.y * 64;
    const int qz = blockIdx.z;
    const int tid = threadIdx.x;
    const int nl = tid >> 6, c = tid & 63;
    const int cc = c0 + c;
    const bool act = cc < cin;
    __shared__ float esl[4][128];
    __shared__ int srcl[512];
    {
        int e0 = g * 2048 + qz * 512;
        for (int i = tid; i < 512; i += 256) srcl[i] = src[e0 + i] - g * 256;
    }
    float wreg[16];
#pragma unroll
    for (int j = 0; j < 16; j++) wreg[j] = act ? Wme[j * cin + cc] : 0.f;
    __syncthreads();
    const float* Hsrc = H2 + (size_t)(g * 256) * ldH + c0;
    const float* Hdst = H2 + (size_t)(g * 256) * ldH + cin + c0;
    for (int i = 0; i < 16; i++) {
        const int vl = qz * 64 + i * 4 + nl;
        {
            const float* ep = es + (size_t)(g * 256 + vl) * 128;
            esl[nl][c] = ep[c];
            esl[nl][64 + c] = ep[64 + c];
        }
        __syncthreads();
        if (act) {
            float hd = Hdst[(size_t)vl * ldH + c];
            float sum = 0.f, sq = 0.f, mx = -INFINITY;
#pragma unroll
            for (int e = 0; e < 8; e++) {
                int sl = srcl[(i * 4 + nl) * 8 + e];
                float m = hd + Hsrc[(size_t)sl * ldH + c];
                float4 e0 = *(const float4*)&esl[nl][e * 16 + 0];
                float4 e1 = *(const float4*)&esl[nl][e * 16 + 4];
                float4 e2 = *(const float4*)&esl[nl][e * 16 + 8];
                float4 e3 = *(const float4*)&esl[nl][e * 16 + 12];
                m = fmaf(e0.x, wreg[0], m);  m = fmaf(e0.y, wreg[1], m);
                m = fmaf(e0.z, wreg[2], m);  m = fmaf(e0.w, wreg[3], m);
                m = fmaf(e1.x, wreg[4], m);  m = fmaf(e1.y, wreg[5], m);
                m = fmaf(e1.z, wreg[6], m);  m = fmaf(e1.w, wreg[7], m);
                m = fmaf(e2.x, wreg[8], m);  m = fmaf(e2.y, wreg[9], m);
                m = fmaf(e2.z, wreg[10], m); m = fmaf(e2.w, wreg[11], m);
                m = fmaf(e3.x, wreg[12], m); m = fmaf(e3.y, wreg[13], m);
                m = fmaf(e3.z, wreg[14], m); m = fmaf(e3.w, wreg[15], m);
                sum += m;
                sq = fmaf(m, m, sq);
                mx = fmaxf(mx, m);
            }
            float mean = sum * 0.125f, msq = sq * 0.125f;
            float stdv = sqrtf(fmaxf(msq - mean * mean, 0.f) + 1e-30f);
            size_t o = (size_t)(g * 256 + vl) * ldX + offX + cc;
            us16 h;
            h = f2bf(sum);  Xh[o] = h;            Xl[o] = f2bf(sum - bf2f(h));
            h = f2bf(mx);   Xh[o + cin] = h;      Xl[o + cin] = f2bf(mx - bf2f(h));
            h = f2bf(stdv); Xh[o + 2 * cin] = h;  Xl[o + 2 * cin] = f2bf(stdv - bf2f(h));
        }
        __syncthreads();
    }
}

// ======================= BatchNorm stats pass 2 =======================
__global__ void bnstats2_k(const float* __restrict__ part, const float* __restrict__ bng,
                           const float* __restrict__ bnb, float* __restrict__ scale,
                           float* __restrict__ shift, int cout)
{
    int c = threadIdx.x;
    if (c >= cout) return;
    float s = 0.f, q = 0.f;
    for (int b = 0; b < 256; b++) { s += part[(size_t)b * cout + c]; q += part[(size_t)(256 + b) * cout + c]; }
    float mean = s / 16384.f;
    float var  = q / 16384.f - mean * mean;
    float sc   = bng[c] / sqrtf(var + 1e-5f);
    scale[c] = sc;
    shift[c] = bnb[c] - mean * sc;
}

// ======================= head =======================
__global__ void rowmax_k(const float* __restrict__ h3, float* __restrict__ nm)
{
    int wave = threadIdx.x >> 6;
    int lane = threadIdx.x & 63;
    int node = blockIdx.x * 4 + wave;
    const float* row = h3 + (size_t)node * 192;
    float m = -INFINITY;
    for (int t = lane; t < 192; t += 64) m = fmaxf(m, row[t]);
#pragma unroll
    for (int off = 32; off > 0; off >>= 1) m = fmaxf(m, __shfl_down(m, off, 64));
    if (lane == 0) nm[node] = m;
}

__global__ __launch_bounds__(256) void g_k(const float* __restrict__ nm,
    const float* __restrict__ W3, const float* __restrict__ b3,
    const float* __restrict__ W4, const float* __restrict__ b4,
    float* __restrict__ g)
{
    __shared__ float row[256];
    __shared__ float t1[64];
    int b = blockIdx.x, tid = threadIdx.x;
    row[tid] = nm[b * 256 + tid];
    __syncthreads();
    if (tid < 64) {
        float a = b3[tid];
        for (int k = 0; k < 256; k++) a = fmaf(row[k], W3[k * 64 + tid], a);
        t1[tid] = fmaxf(a, 0.f);
    }
    __syncthreads();
    float a = b4[tid];
    for (int j = 0; j < 64; j++) a = fmaf(t1[j], W4[j * 256 + tid], a);
    g[b * 256 + tid] = 1.f / (1.f + expf(-a));
}

// ======================= masked softmax (parallel, 2-pass; sm1 caches logits in out) ====
__global__ __launch_bounds__(256) void sm1_k(const float* __restrict__ mask,
    const float* __restrict__ g, const float* __restrict__ h3, float* __restrict__ part,
    float* __restrict__ out)
{
    int b = blockIdx.x, s = blockIdx.y, tid = threadIdx.x;
    float l[24];
#pragma unroll
    for (int t = 0; t < 24; t++) {
        int i = s * 6144 + t * 256 + tid;
        size_t idx = (size_t)b * 49152 + i;
        float mk = mask[idx];
        l[t] = (mk == 0.f) ? -1e5f : g[b * 256 + i / 192] * h3[idx];
        out[idx] = l[t];
    }
    float m = -INFINITY;
#pragma unroll
    for (int t = 0; t < 24; t++) m = fmaxf(m, l[t]);
    __shared__ float red[256];
    red[tid] = m; __syncthreads();
    for (int st = 128; st > 0; st >>= 1) { if (tid < st) red[tid] = fmaxf(red[tid], red[tid + st]); __syncthreads(); }
    m = red[0]; __syncthreads();
    float z = 0.f;
#pragma unroll
    for (int t = 0; t < 24; t++) z += expf(l[t] - m);
    red[tid] = z; __syncthreads();
    for (int st = 128; st > 0; st >>= 1) { if (tid < st) red[tid] += red[tid + st]; __syncthreads(); }
    if (tid == 0) { part[(b * 8 + s) * 2] = m; part[(b * 8 + s) * 2 + 1] = red[0]; }
}

__global__ void sm2_k(const float* __restrict__ part, float* __restrict__ mz)
{
    int b = threadIdx.x;
    if (b >= 64) return;
    float M = -INFINITY;
    for (int s = 0; s < 8; s++) M = fmaxf(M, part[(b * 8 + s) * 2]);
    float Z = 0.f;
    for (int s = 0; s < 8; s++) Z += part[(b * 8 + s) * 2 + 1] * expf(part[(b * 8 + s) * 2] - M);
    mz[b * 2] = M;
    mz[b * 2 + 1] = 1.f / Z;
}

__global__ __launch_bounds__(256) void sm3_k(const float* __restrict__ mz,
    float* __restrict__ out)
{
    int b = blockIdx.x, s = blockIdx.y, tid = threadIdx.x;
    float M = mz[b * 2], invZ = mz[b * 2 + 1];
#pragma unroll
    for (int t = 0; t < 24; t++) {
        int i = s * 6144 + t * 256 + tid;
        size_t idx = (size_t)b * 49152 + i;
        float v = out[idx];
        out[idx] = expf(v - M) * invZ;
    }
}

// ======================= launcher =======================
extern "C" void kernel_launch(void* const* d_in, const int* in_sizes, int n_in,
                              void* d_out, int out_size, void* d_ws, size_t ws_size,
                              hipStream_t stream)
{
    const float* ns   = (const float*)d_in[0];
    const float* es   = (const float*)d_in[1];
    const float* dm   = (const float*)d_in[2];
    const float* mask = (const float*)d_in[3];
    const int*   src  = (const int*)d_in[4];
    const float* Wm1 = (const float*)d_in[6],  *bm1 = (const float*)d_in[7];
    const float* Wu1 = (const float*)d_in[8],  *bu1 = (const float*)d_in[9];
    const float* bng1= (const float*)d_in[10], *bnb1= (const float*)d_in[11];
    const float* Wx1 = (const float*)d_in[12], *bx1 = (const float*)d_in[13];
    const float* Wm2 = (const float*)d_in[14], *bm2 = (const float*)d_in[15];
    const float* Wu2 = (const float*)d_in[16], *bu2 = (const float*)d_in[17];
    const float* bng2= (const float*)d_in[18], *bnb2= (const float*)d_in[19];
    const float* Wx2 = (const float*)d_in[20], *bx2 = (const float*)d_in[21];
    const float* Wm3 = (const float*)d_in[22], *bm3 = (const float*)d_in[23];
    const float* Wu3 = (const float*)d_in[24], *bu3 = (const float*)d_in[25];
    const float* bng3= (const float*)d_in[26], *bnb3= (const float*)d_in[27];
    const float* Wx3 = (const float*)d_in[28], *bx3 = (const float*)d_in[29];
    const float* W1 = (const float*)d_in[30], *b1 = (const float*)d_in[31];
    const float* W2 = (const float*)d_in[32], *b2 = (const float*)d_in[33];
    const float* W3 = (const float*)d_in[34], *b3 = (const float*)d_in[35];
    const float* W4 = (const float*)d_in[36], *b4 = (const float*)d_in[37];
    float* out = (float*)d_out;

    const int N = NNODE;
    char* base = (char*)d_ws;
    size_t off = 0;
    auto alloc = [&](size_t bytes) -> void* {
        void* p = base + off;
        off = (off + bytes + 255) & ~(size_t)255;
        return p;
    };
    us16* Xh = (us16*)alloc((size_t)N * 1728 * 2);
    us16* Xl = (us16*)alloc((size_t)N * 1728 * 2);
    float* H2   = (float*)alloc((size_t)N * 1216 * 4);   // [Hsrc|Hdst|u_partial]
    us16* uh = (us16*)alloc((size_t)N * 384 * 2);
    us16* ul = (us16*)alloc((size_t)N * 384 * 2);
    us16* dmh = (us16*)alloc((size_t)N * 256 * 2);
    us16* dml = (us16*)alloc((size_t)N * 256 * 2);
    float* h3b  = (float*)alloc((size_t)N * 192 * 4);
    float* d2f  = (float*)alloc((size_t)N * 32 * 4);
    float* part = (float*)alloc((size_t)512 * 384 * 4);
    float* scale= (float*)alloc(384 * 4);
    float* shift= (float*)alloc(384 * 4);
    float* bias2= (float*)alloc(384 * 4);
    float* b12  = (float*)alloc(32 * 4);
    float* biasMU1 = (float*)alloc(640 * 4);
    float* biasMU2 = (float*)alloc(1216 * 4);
    float* biasMU3 = (float*)alloc(960 * 4);
    float* nm   = (float*)alloc((size_t)N * 4);
    float* gbuf = (float*)alloc((size_t)N * 4);
    float* smp  = (float*)alloc(64 * 8 * 2 * 4);
    float* smz  = (float*)alloc(64 * 2 * 4);
    auto aw = [&](size_t elems) -> us16* { return (us16*)alloc(elems * 2); };
    us16 *BM1h = aw((size_t)640 * 4 * 32),    *BM1l = aw((size_t)640 * 4 * 32);
    us16 *BA1h = aw((size_t)384 * 12 * 32),   *BA1l = aw((size_t)384 * 12 * 32);
    us16 *BX1h = aw((size_t)384 * 12 * 32),   *BX1l = aw((size_t)384 * 12 * 32);
    us16 *BM2h = aw((size_t)1280 * 14 * 32),  *BM2l = aw((size_t)1280 * 14 * 32);
    us16 *BA2h = aw((size_t)384 * 40 * 32),   *BA2l = aw((size_t)384 * 40 * 32);
    us16 *BX2h = aw((size_t)384 * 12 * 32),   *BX2l = aw((size_t)384 * 12 * 32);
    us16 *BM3h = aw((size_t)1024 * 12 * 32),  *BM3l = aw((size_t)1024 * 12 * 32);
    us16 *BA3h = aw((size_t)192 * 36 * 32),   *BA3l = aw((size_t)192 * 36 * 32);
    us16 *BX3h = aw((size_t)192 * 6 * 32),    *BX3l = aw((size_t)192 * 6 * 32);
    us16 *B12h = aw((size_t)64 * 8 * 32),     *B12l = aw((size_t)64 * 8 * 32);

    auto gp = [](size_t n) { return dim3((unsigned)((n + 255) / 256)); };
    auto fsec = [](us16* b, int c0, int KC) { return b + (size_t)(c0 / 16) * KC * 512; };

    // ---- fused fragment prep descriptors ----
    FrPack pk;
    int nd = 0, blk = 0;
    auto addD = [&](const float* W, us16* Bh, us16* Bl, int ldW, int Kv, int Nv, int Na, int KC, int mode, int cin) {
        pk.d[nd] = {W, Bh, Bl, ldW, Kv, Nv, Na, KC, mode, cin, blk};
        blk += (Na * KC * 32 + 255) / 256;
        nd++;
    };
    addD(Wm1,             fsec(BM1h,0,4),    fsec(BM1l,0,4),    128, 128, 128, 128, 4, 0, 0);
    addD(Wm1 + 128*128,   fsec(BM1h,128,4),  fsec(BM1l,128,4),  128, 128, 128, 128, 4, 0, 0);
    addD(Wu1,             fsec(BM1h,256,4),  fsec(BM1l,256,4),  384, 128, 384, 384, 4, 0, 0);
    addD(Wu1,             BA1h, BA1l,        0,   0,   384, 384, 12, 1, 128);
    addD(Wm2,             fsec(BM2h,0,14),   fsec(BM2l,0,14),   416, 416, 416, 416, 14, 0, 0);
    addD(Wm2 + 416*416,   fsec(BM2h,416,14), fsec(BM2l,416,14), 416, 416, 416, 416, 14, 0, 0);
    addD(Wu2,             fsec(BM2h,832,14), fsec(BM2l,832,14), 384, 416, 384, 384, 14, 0, 0);
    addD(nullptr,         fsec(BM2h,1216,14),fsec(BM2l,1216,14),0,   0,   0,   64,  14, 2, 0);
    addD(Wu2,             BA2h, BA2l,        0,   0,   384, 384, 40, 1, 416);
    addD(Wm3,             fsec(BM3h,0,12),   fsec(BM3l,0,12),   384, 384, 384, 384, 12, 0, 0);
    addD(Wm3 + 384*384,   fsec(BM3h,384,12), fsec(BM3l,384,12), 384, 384, 384, 384, 12, 0, 0);
    addD(Wu3,             fsec(BM3h,768,12), fsec(BM3l,768,12), 192, 384, 192, 192, 12, 0, 0);
    addD(nullptr,         fsec(BM3h,960,12), fsec(BM3l,960,12), 0,   0,   0,   64,  12, 2, 0);
    addD(Wu3,             BA3h, BA3l,        0,   0,   192, 192, 36, 1, 384);
    pk.nd = nd;

    // ---- input splits + preps ----
    csplit2_k<<<8192 + 16384, 256, 0, stream>>>(ns, Xh, Xl, dm, dmh, dml);
    prep_fr_all<<<blk, 256, 0, stream>>>(pk);
    w12frag_k<<<gp(64 * 8 * 32), 256, 0, stream>>>(W1, W2, B12h, B12l);
    bias12_k<<<1, 32, 0, stream>>>(b1, W2, b2, b12);
    prep_biasMU<<<gp(640), 256, 0, stream>>>(bm1, bu1, biasMU1, 128, 384);
    prep_biasMU<<<gp(1216), 256, 0, stream>>>(bm2, bu2, biasMU2, 416, 384);
    prep_biasMU<<<gp(960), 256, 0, stream>>>(bm3, bu3, biasMU3, 384, 192);

    // ---- d2 = dm @ W12 + b12 ----
    mgemm9<0, 0, 0, 1, 0><<<256, 256, 0, stream>>>(1, dmh, dml, 256, 256, B12h, B12l, 8,
        nullptr, 0, d2f, nullptr, nullptr, 32, 32, b12, nullptr, 0);

    // ================= layer 1 (cin=128, X ld 512, H2 ld 640) =================
    mgemm9<0, 0, 0, 2, 0><<<256 * 5, 256, 0, stream>>>(5, Xh, Xl, 512, 128, BM1h, BM1l, 4,
        nullptr, 0, H2, nullptr, nullptr, 640, 640, biasMU1, nullptr, 0);
    agg2_k<<<dim3(64, 2, 4), 256, 0, stream>>>(H2, es, src, Wm1 + 2 * 128 * 128, Xh, Xl, 128, 640, 512, 128);
    mgemm9<0, 1, 1, 2, 1><<<256 * 3, 256, 0, stream>>>(3, Xh + 128, Xl + 128, 512, 384, BA1h, BA1l, 12,
        H2 + 256, 640, nullptr, uh, ul, 384, 384, nullptr, part, 384);
    bnstats2_k<<<1, 384, 0, stream>>>(part, bng1, bnb1, scale, shift, 384);
    fusedwx_k<<<576 + 384, 256, 0, stream>>>(Wx1, scale, shift, bx1, BX1h, BX1l, 384, 384, 12, 576, bias2);
    mgemm9<1, 1, 0, 2, 0><<<256 * 3, 256, 0, stream>>>(3, uh, ul, 384, 384, BX1h, BX1l, 12,
        nullptr, 0, nullptr, Xh, Xl, 1728, 384, bias2, nullptr, 0);   // h2a -> X2[0:384)
    csplit_k<<<gp((size_t)N * 32), 256, 0, stream>>>(d2f, 32, 32, Xh, Xl, 1728, 384);  // d2 -> X2[384:416)

    // ================= layer 2 (cin=416, X ld 1728, H2 ld 1216) =================
    mgemm9<0, 0, 0, 2, 0><<<256 * 10, 256, 0, stream>>>(10, Xh, Xl, 1728, 416, BM2h, BM2l, 14,
        nullptr, 0, H2, nullptr, nullptr, 1216, 1216, biasMU2, nullptr, 0);
    agg2_k<<<dim3(64, 7, 4), 256, 0, stream>>>(H2, es, src, Wm2 + 2 * 416 * 416, Xh, Xl, 416, 1216, 1728, 416);
    mgemm9<0, 1, 1, 2, 1><<<256 * 3, 256, 0, stream>>>(3, Xh + 416, Xl + 416, 1728, 1248, BA2h, BA2l, 40,
        H2 + 832, 1216, nullptr, uh, ul, 384, 384, nullptr, part, 384);
    bnstats2_k<<<1, 384, 0, stream>>>(part, bng2, bnb2, scale, shift, 384);
    fusedwx_k<<<576 + 384, 256, 0, stream>>>(Wx2, scale, shift, bx2, BX2h, BX2l, 384, 384, 12, 576, bias2);
    mgemm9<1, 1, 0, 2, 0><<<256 * 3, 256, 0, stream>>>(3, uh, ul, 384, 384, BX2h, BX2l, 12,
        nullptr, 0, nullptr, Xh, Xl, 1536, 384, bias2, nullptr, 0);   // h3-in -> X3[0:384)

    // ================= layer 3 (cin=384, X ld 1536, H2 ld 960) =================
    mgemm9<0, 0, 0, 2, 0><<<256 * 8, 256, 0, stream>>>(8, Xh, Xl, 1536, 384, BM3h, BM3l, 12,
        nullptr, 0, H2, nullptr, nullptr, 960, 960, biasMU3, nullptr, 0);
    agg2_k<<<dim3(64, 6, 4), 256, 0, stream>>>(H2, es, src, Wm3 + 2 * 384 * 384, Xh, Xl, 384, 960, 1536, 384);
    mgemm9<0, 1, 1, 1, 1><<<256 * 3, 256, 0, stream>>>(3, Xh + 384, Xl + 384, 1536, 1152, BA3h, BA3l, 36,
        H2 + 768, 960, nullptr, uh, ul, 192, 192, nullptr, part, 192);
    bnstats2_k<<<1, 384, 0, stream>>>(part, bng3, bnb3, scale, shift, 192);
    fusedwx_k<<<144 + 192, 256, 0, stream>>>(Wx3, scale, shift, bx3, BX3h, BX3l, 192, 192, 6, 144, bias2);
    mgemm9<2, 0, 0, 1, 0><<<256 * 3, 256, 0, stream>>>(3, uh, ul, 192, 192, BX3h, BX3l, 6,
        nullptr, 0, h3b, nullptr, nullptr, 192, 192, bias2, nullptr, 0);

    // ---- head ----
    rowmax_k<<<N / 4, 256, 0, stream>>>(h3b, nm);
    g_k<<<64, 256, 0, stream>>>(nm, W3, b3, W4, b4, gbuf);
    sm1_k<<<dim3(64, 8), 256, 0, stream>>>(mask, gbuf, h3b, smp, out);
    sm2_k<<<1, 64, 0, stream>>>(smp, smz);
    sm3_k<<<dim3(64, 8), 256, 0, stream>>>(smz, out);
}

// Round 15
// 608.596 us; speedup vs baseline: 1.2819x; 1.0176x over previous
//
#include <hip/hip_runtime.h>
#include <hip/hip_bf16.h>

#define NNODE 16384

typedef short v8s __attribute__((ext_vector_type(8)));
typedef float v4f __attribute__((ext_vector_type(4)));
typedef unsigned short us16;

__device__ __forceinline__ us16 f2bf(float v) {
    unsigned u = __float_as_uint(v);
    unsigned r = (u + 0x7FFF + ((u >> 16) & 1)) >> 16;
    return (us16)r;
}
__device__ __forceinline__ float bf2f(us16 s) {
    return __uint_as_float(((unsigned)s) << 16);
}

// ======================= split-bf16 MFMA GEMM v9 =======================
// A in LDS (hi/lo, XOR swizzle), BM=64, NB col-groups of 64, 4 waves (2x2).
// Reg-prefetch pipeline; B in MFMA fragment order (coalesced per-wave loads).
// XCD-chunked 1-D grid swizzle (nwg%8==0). Optional fused BN-stats (STATS=1).
// NOTE: launch_bounds (256,3) — (256,4) forces reg cap 128 (VGPR+AGPR unified)
// and SPILLS (~140MB scratch traffic/dispatch, round-13 regression).
// 3-term split: AhBh + AlBh + AhBl. ACC: += f32 CfIn. OUT: 0=f32, 1=split bf16.
template<int EPI, int OUT, int ACC, int NB, int STATS>
__global__ __launch_bounds__(256, 3)
void mgemm9(int nyPanels,
            const us16* __restrict__ Ah, const us16* __restrict__ Al,
            int ldA, int K,
            const us16* __restrict__ Bh, const us16* __restrict__ Bl, int KC,
            const float* __restrict__ CfIn, int ldCin,
            float* __restrict__ Cf, us16* __restrict__ Ch, us16* __restrict__ Cl,
            int ldC, int Ncol, const float* __restrict__ bias,
            float* __restrict__ statsPart, int statsStride)
{
    __shared__ __align__(16) us16 AhS[64 * 64];
    __shared__ __align__(16) us16 AlS[64 * 64];
    const int nwg = gridDim.x;
    const int bid = blockIdx.x;
    const int wgid = (bid & 7) * (nwg >> 3) + (bid >> 3);   // XCD-chunked (nwg%8==0)
    const int bm  = (wgid / nyPanels) * 64;
    const int bn0 = (wgid % nyPanels) * (64 * NB);
    const int tid = threadIdx.x;
    const int lane = tid & 63, wid = tid >> 6;
    const int wm = wid >> 1, wn = wid & 1;
    const int r16 = lane & 15, q = lane >> 4;
    v4f acc[NB][2][2];
#pragma unroll
    for (int b = 0; b < NB; b++)
#pragma unroll
        for (int i = 0; i < 2; i++)
#pragma unroll
            for (int j = 0; j < 2; j++) acc[b][i][j] = (v4f){0.f, 0.f, 0.f, 0.f};

    const int srow = tid >> 3;            // 0..31
    const int sc8  = tid & 7;             // 16B chunk in 64-elem row
    const int cbw  = (bn0 >> 4) + wn * 2;
    const int nK = (K + 63) >> 6;

    // prefetch registers (tile to be written next)
    v8s ph[2], pl[2];
    {
        int gk = sc8 * 8;
#pragma unroll
        for (int p = 0; p < 2; p++) {
            int row = p * 32 + srow;
            ph[p] = (v8s){0,0,0,0,0,0,0,0};
            pl[p] = (v8s){0,0,0,0,0,0,0,0};
            if (gk < K) {
                size_t go = (size_t)(bm + row) * ldA + gk;
                ph[p] = *(const v8s*)(const void*)(Ah + go);
                pl[p] = *(const v8s*)(const void*)(Al + go);
            }
        }
    }

    for (int s = 0; s < nK; s++) {
        const int k0 = s << 6;
        __syncthreads();   // all waves done reading previous tile
        // ---- write prefetched tile s ----
#pragma unroll
        for (int p = 0; p < 2; p++) {
            int row = p * 32 + srow;
            int bo = row * 128 + ((sc8 * 16) ^ ((row & 7) << 4));
            *(v8s*)(void*)((char*)AhS + bo) = ph[p];
            *(v8s*)(void*)((char*)AlS + bo) = pl[p];
        }
        __syncthreads();   // tile visible
        // ---- B fragment loads for tile s (ALL, before prefetch) ----
        v8s bfh[2][NB][2], bfl[2][NB][2];
#pragma unroll
        for (int kc = 0; kc < 2; kc++) {
            int kchunk = (k0 >> 5) + kc;
#pragma unroll
            for (int nb = 0; nb < NB; nb++)
#pragma unroll
                for (int nf = 0; nf < 2; nf++) {
                    int colblk = cbw + nb * 4 + nf;
                    size_t fo = ((size_t)(colblk * KC + kchunk) * 64 + lane) * 8;
                    bfh[kc][nb][nf] = *(const v8s*)(const void*)(Bh + fo);
                    bfl[kc][nb][nf] = *(const v8s*)(const void*)(Bl + fo);
                }
        }
        // ---- prefetch tile s+1 into regs (stays in flight through compute) ----
        if (s + 1 < nK) {
            int gk = (k0 + 64) + sc8 * 8;
#pragma unroll
            for (int p = 0; p < 2; p++) {
                int row = p * 32 + srow;
                v8s hv = (v8s){0,0,0,0,0,0,0,0};
                v8s lv = (v8s){0,0,0,0,0,0,0,0};
                if (gk < K) {
                    size_t go = (size_t)(bm + row) * ldA + gk;
                    hv = *(const v8s*)(const void*)(Ah + go);
                    lv = *(const v8s*)(const void*)(Al + go);
                }
                ph[p] = hv;
                pl[p] = lv;
            }
        }
        // ---- compute ----
#pragma unroll
        for (int kc = 0; kc < 2; kc++) {
#pragma unroll
            for (int mf = 0; mf < 2; mf++) {
                int arow = wm * 32 + mf * 16 + r16;
                int ao = arow * 128 + (((kc * 64) + q * 16) ^ ((arow & 7) << 4));
                v8s ah = *(const v8s*)(const void*)((const char*)AhS + ao);
                v8s al = *(const v8s*)(const void*)((const char*)AlS + ao);
#pragma unroll
                for (int nb = 0; nb < NB; nb++)
#pragma unroll
                    for (int nf = 0; nf < 2; nf++) {
                        acc[nb][mf][nf] = __builtin_amdgcn_mfma_f32_16x16x32_bf16(ah, bfh[kc][nb][nf], acc[nb][mf][nf], 0, 0, 0);
                        acc[nb][mf][nf] = __builtin_amdgcn_mfma_f32_16x16x32_bf16(al, bfh[kc][nb][nf], acc[nb][mf][nf], 0, 0, 0);
                        acc[nb][mf][nf] = __builtin_amdgcn_mfma_f32_16x16x32_bf16(ah, bfl[kc][nb][nf], acc[nb][mf][nf], 0, 0, 0);
                    }
            }
        }
    }
    // ---- epilogue ----
    float csum[NB][2], csq[NB][2];
#pragma unroll
    for (int nb = 0; nb < NB; nb++)
#pragma unroll
        for (int nf = 0; nf < 2; nf++) { csum[nb][nf] = 0.f; csq[nb][nf] = 0.f; }
#pragma unroll
    for (int nb = 0; nb < NB; nb++)
#pragma unroll
        for (int mf = 0; mf < 2; mf++)
#pragma unroll
            for (int nf = 0; nf < 2; nf++) {
                int col = bn0 + nb * 64 + wn * 32 + nf * 16 + r16;
                if (col < Ncol) {
                    float bv = bias ? bias[col] : 0.f;
#pragma unroll
                    for (int r = 0; r < 4; r++) {
                        int row = bm + wm * 32 + mf * 16 + q * 4 + r;
                        float v = acc[nb][mf][nf][r] + bv;
                        if (ACC) v += CfIn[(size_t)row * ldCin + col];
                        if (EPI == 1) v = fmaxf(v, 0.f);
                        if (EPI == 2) v = (v > 0.f) ? v : 0.01f * v;
                        if (STATS) { csum[nb][nf] += v; csq[nb][nf] = fmaf(v, v, csq[nb][nf]); }
                        size_t o = (size_t)row * ldC + col;
                        if (OUT == 0) {
                            Cf[o] = v;
                        } else {
                            us16 h = f2bf(v);
                            Ch[o] = h;
                            Cl[o] = f2bf(v - bf2f(h));
                        }
                    }
                }
            }
    if (STATS) {
        __syncthreads();
        float* sbs = (float*)AhS;   // per-(wm,wn,nb,nf,r16) 32-row sums
        float* sbq = (float*)AlS;
#pragma unroll
        for (int nb = 0; nb < NB; nb++)
#pragma unroll
            for (int nf = 0; nf < 2; nf++) {
                float s = csum[nb][nf];
                float t = csq[nb][nf];
                s += __shfl_down(s, 16, 64);
                s += __shfl_down(s, 32, 64);
                t += __shfl_down(t, 16, 64);
                t += __shfl_down(t, 32, 64);
                if (q == 0) {
                    int si = ((wm * 2 + wn) * NB + nb) * 32 + nf * 16 + r16;
                    sbs[si] = s;
                    sbq[si] = t;
                }
            }
        __syncthreads();
        if (wm == 0 && q == 0) {
            int rowblk = bm >> 6;
#pragma unroll
            for (int nb = 0; nb < NB; nb++)
#pragma unroll
                for (int nf = 0; nf < 2; nf++) {
                    int i0 = ((0 * 2 + wn) * NB + nb) * 32 + nf * 16 + r16;
                    int i1 = ((1 * 2 + wn) * NB + nb) * 32 + nf * 16 + r16;
                    int col = bn0 + nb * 64 + wn * 32 + nf * 16 + r16;
                    statsPart[(size_t)rowblk * statsStride + col] = sbs[i0] + sbs[i1];
                    statsPart[(size_t)(256 + rowblk) * statsStride + col] = sbq[i0] + sbq[i1];
                }
        }
    }
}

// ======================= fused fragment-order weight prep =======================
struct FrD {
    const float* W;
    us16* Bh;
    us16* Bl;
    int ldW, Kv, Nv, Na, KC, mode, cin, blk0;
};
struct FrPack { FrD d[16]; int nd; };

__global__ __launch_bounds__(256) void prep_fr_all(FrPack p)
{
    int b = blockIdx.x;
    int i = 0;
    for (int j = 1; j < p.nd; j++) if (b >= p.d[j].blk0) i = j;
    const FrD dd = p.d[i];
    int idx = (b - dd.blk0) * 256 + threadIdx.x;
    if (idx >= dd.Na * dd.KC * 32) return;
    int e = idx & 7, lane = (idx >> 3) & 63, rem = idx >> 9;
    int kchunk = rem % dd.KC, colblk = rem / dd.KC;
    int n = colblk * 16 + (lane & 15);
    int k = kchunk * 32 + (lane >> 4) * 8 + e;
    float v = 0.f;
    if (dd.mode == 0) {
        if (k < dd.Kv && n < dd.Nv) v = dd.W[(size_t)k * dd.ldW + n];
    } else if (dd.mode == 1) {
        int cin = dd.cin, cout = dd.Nv;
        if (n < cout && k < 3 * cin) {
            if (k < cin)          v = dd.W[(size_t)(cin + k) * cout + n] * 0.125f + dd.W[(size_t)(3 * cin + k) * cout + n];
            else if (k < 2 * cin) v = dd.W[(size_t)(2 * cin + (k - cin)) * cout + n];
            else                  v = dd.W[(size_t)(4 * cin + (k - 2 * cin)) * cout + n];
        }
    } // mode 2: zero
    us16 h = f2bf(v);
    dd.Bh[idx] = h;
    dd.Bl[idx] = f2bf(v - bf2f(h));
}

// fused Wx prep (BN-scaled, fragment order) + bias2 reduction
__global__ __launch_bounds__(256) void fusedwx_k(
    const float* __restrict__ Wx, const float* __restrict__ scale,
    const float* __restrict__ shift, const float* __restrict__ bx,
    us16* __restrict__ Bh, us16* __restrict__ Bl,
    int K, int N, int KC, int prepBlocks, float* __restrict__ bias2)
{
    if ((int)blockIdx.x < prepBlocks) {
        int idx = blockIdx.x * 256 + threadIdx.x;
        if (idx >= N * KC * 32) return;
        int e = idx & 7, lane = (idx >> 3) & 63, rem = idx >> 9;
        int kchunk = rem % KC, colblk = rem / KC;
        int n = colblk * 16 + (lane & 15);
        int k = kchunk * 32 + (lane >> 4) * 8 + e;
        float v = (k < K && n < N) ? Wx[(size_t)k * N + n] * scale[k] : 0.f;
        us16 h = f2bf(v);
        Bh[idx] = h;
        Bl[idx] = f2bf(v - bf2f(h));
    } else {
        int n = blockIdx.x - prepBlocks;
        int tid = threadIdx.x;
        float s = 0.f;
        for (int k = tid; k < K; k += 256) s = fmaf(shift[k], Wx[(size_t)k * N + n], s);
        __shared__ float red[256];
        red[tid] = s; __syncthreads();
        for (int st = 128; st > 0; st >>= 1) { if (tid < st) red[tid] += red[tid + st]; __syncthreads(); }
        if (tid == 0) bias2[n] = red[0] + bx[n];
    }
}

// W12 = W1@W2 in fragment order (K=256, N alloc 64 valid 32, KC=8)
__global__ void w12frag_k(const float* __restrict__ W1, const float* __restrict__ W2,
                          us16* __restrict__ Bh, us16* __restrict__ Bl)
{
    int idx = blockIdx.x * 256 + threadIdx.x;
    if (idx >= 64 * 8 * 32) return;
    int e = idx & 7, lane = (idx >> 3) & 63, rem = idx >> 9;
    int kchunk = rem % 8, colblk = rem / 8;
    int n = colblk * 16 + (lane & 15);
    int k = kchunk * 32 + (lane >> 4) * 8 + e;
    float v = 0.f;
    if (n < 32 && k < 256) {
        for (int j = 0; j < 64; j++) v = fmaf(W1[(size_t)k * 64 + j], W2[(size_t)j * 32 + n], v);
    }
    us16 h = f2bf(v);
    Bh[idx] = h;
    Bl[idx] = f2bf(v - bf2f(h));
}

// b12[n] = b2[n] + b1 @ W2[:,n]
__global__ void bias12_k(const float* __restrict__ b1, const float* __restrict__ W2,
                         const float* __restrict__ b2, float* __restrict__ b12)
{
    int n = threadIdx.x;
    if (n >= 32) return;
    float s = b2[n];
    for (int j = 0; j < 64; j++) s = fmaf(b1[j], W2[(size_t)j * 32 + n], s);
    b12[n] = s;
}

// concat bias for merged GEMM: [0]*cin ++ bm ++ bu
__global__ void prep_biasMU(const float* __restrict__ bm, const float* __restrict__ bu,
                            float* __restrict__ o, int cin, int cout)
{
    int i = blockIdx.x * 256 + threadIdx.x;
    if (i >= 2 * cin + cout) return;
    float v;
    if (i < cin)          v = 0.f;
    else if (i < 2 * cin) v = bm[i - cin];
    else                  v = bu[i - 2 * cin];
    o[i] = v;
}

// fused input splits: ns -> X1 (ld512 off0), dm -> dm planes (ld256)
__global__ void csplit2_k(const float* __restrict__ ns, us16* __restrict__ Xh, us16* __restrict__ Xl,
                          const float* __restrict__ dm, us16* __restrict__ Dh, us16* __restrict__ Dl)
{
    int b = blockIdx.x;
    if (b < 8192) {
        int idx = b * 256 + threadIdx.x;          // N*128
        int rrow = idx >> 7, c = idx & 127;
        float v = ns[idx];
        us16 h = f2bf(v);
        size_t o = (size_t)rrow * 512 + c;
        Xh[o] = h;
        Xl[o] = f2bf(v - bf2f(h));
    } else {
        int idx = (b - 8192) * 256 + threadIdx.x; // N*256
        float v = dm[idx];
        us16 h = f2bf(v);
        Dh[idx] = h;
        Dl[idx] = f2bf(v - bf2f(h));
    }
}

// f32 [16384, w] (ld ldS) -> split planes at column offset offX
__global__ void csplit_k(const float* __restrict__ src, int ldS, int w,
                         us16* __restrict__ Xh, us16* __restrict__ Xl,
                         int ldX, int offX)
{
    int idx = blockIdx.x * 256 + threadIdx.x;
    if (idx >= NNODE * w) return;
    int rrow = idx / w, c = idx - rrow * w;
    float v = src[(size_t)rrow * ldS + c];
    us16 h = f2bf(v);
    size_t o = (size_t)rrow * ldX + offX + c;
    Xh[o] = h;
    Xl[o] = f2bf(v - bf2f(h));
}

// ======================= PNA aggregation (split-bf16 output into X) =======================
__global__ __launch_bounds__(256)
void agg2_k(const float* __restrict__ H2, const float* __restrict__ es,
            const int* __restrict__ src, const float* __restrict__ Wme,
            us16* __restrict__ Xh, us16* __restrict__ Xl,
            int cin, int ldH, int ldX, int offX)
{
    const int g = blockIdx.x;
    const int c0 = blockIdx.y * 64;
    const int qz = blockIdx.z;
    const int tid = threadIdx.x;
    const int nl = tid >> 6, c = tid & 63;
    const int cc = c0 + c;
    const bool act = cc < cin;
    __shared__ float esl[4][128];
    __shared__ int srcl[512];
    {
        int e0 = g * 2048 + qz * 512;
        for (int i = tid; i < 512; i += 256) srcl[i] = src[e0 + i] - g * 256;
    }
    float wreg[16];
#pragma unroll
    for (int j = 0; j < 16; j++) wreg[j] = act ? Wme[j * cin + cc] : 0.f;
    __syncthreads();
    const float* Hsrc = H2 + (size_t)(g * 256) * ldH + c0;
    const float* Hdst = H2 + (size_t)(g * 256) * ldH + cin + c0;
    for (int i = 0; i < 16; i++) {
        const int vl = qz * 64 + i * 4 + nl;
        {
            const float* ep = es + (size_t)(g * 256 + vl) * 128;
            esl[nl][c] = ep[c];
            esl[nl][64 + c] = ep[64 + c];
        }
        __syncthreads();
        if (act) {
            float hd = Hdst[(size_t)vl * ldH + c];
            float sum = 0.f, sq = 0.f, mx = -INFINITY;
#pragma unroll
            for (int e = 0; e < 8; e++) {
                int sl = srcl[(i * 4 + nl) * 8 + e];
                float m = hd + Hsrc[(size_t)sl * ldH + c];
                float4 e0 = *(const float4*)&esl[nl][e * 16 + 0];
                float4 e1 = *(const float4*)&esl[nl][e * 16 + 4];
                float4 e2 = *(const float4*)&esl[nl][e * 16 + 8];
                float4 e3 = *(const float4*)&esl[nl][e * 16 + 12];
                m = fmaf(e0.x, wreg[0], m);  m = fmaf(e0.y, wreg[1], m);
                m = fmaf(e0.z, wreg[2], m);  m = fmaf(e0.w, wreg[3], m);
                m = fmaf(e1.x, wreg[4], m);  m = fmaf(e1.y, wreg[5], m);
                m = fmaf(e1.z, wreg[6], m);  m = fmaf(e1.w, wreg[7], m);
                m = fmaf(e2.x, wreg[8], m);  m = fmaf(e2.y, wreg[9], m);
                m = fmaf(e2.z, wreg[10], m); m = fmaf(e2.w, wreg[11], m);
                m = fmaf(e3.x, wreg[12], m); m = fmaf(e3.y, wreg[13], m);
                m = fmaf(e3.z, wreg[14], m); m = fmaf(e3.w, wreg[15], m);
                sum += m;
                sq = fmaf(m, m, sq);
                mx = fmaxf(mx, m);
            }
            float mean = sum * 0.125f, msq = sq * 0.125f;
            float stdv = sqrtf(fmaxf(msq - mean * mean, 0.f) + 1e-30f);
            size_t o = (size_t)(g * 256 + vl) * ldX + offX + cc;
            us16 h;
            h = f2bf(sum);  Xh[o] = h;            Xl[o] = f2bf(sum - bf2f(h));
            h = f2bf(mx);   Xh[o + cin] = h;      Xl[o + cin] = f2bf(mx - bf2f(h));
            h = f2bf(stdv); Xh[o + 2 * cin] = h;  Xl[o + 2 * cin] = f2bf(stdv - bf2f(h));
        }
        __syncthreads();
    }
}

// ======================= BatchNorm stats pass 2 (parallel, coalesced) =================
// grid = ceil(cout/64) blocks, 256 threads = 64 cols x 4 row-groups of 64 rows.
// Deterministic: fixed per-group serial sum, fixed-order 4-way combine.
__global__ __launch_bounds__(256) void bnstats2p_k(const float* __restrict__ part,
    const float* __restrict__ bng, const float* __restrict__ bnb,
    float* __restrict__ scale, float* __restrict__ shift, int cout)
{
    int l = threadIdx.x & 63;
    int rg = threadIdx.x >> 6;           // 0..3
    int c = blockIdx.x * 64 + l;
    float s = 0.f, q = 0.f;
    if (c < cout) {
        for (int r = rg * 64; r < rg * 64 + 64; r++) {
            s += part[(size_t)r * cout + c];
            q += part[(size_t)(256 + r) * cout + c];
        }
    }
    __shared__ float ss[4][64], sq[4][64];
    ss[rg][l] = s;
    sq[rg][l] = q;
    __syncthreads();
    if (rg == 0 && c < cout) {
        float S = ss[0][l] + ss[1][l] + ss[2][l] + ss[3][l];
        float Q = sq[0][l] + sq[1][l] + sq[2][l] + sq[3][l];
        float mean = S / 16384.f;
        float var  = Q / 16384.f - mean * mean;
        float sc   = bng[c] / sqrtf(var + 1e-5f);
        scale[c] = sc;
        shift[c] = bnb[c] - mean * sc;
    }
}

// ======================= head =======================
__global__ void rowmax_k(const float* __restrict__ h3, float* __restrict__ nm)
{
    int wave = threadIdx.x >> 6;
    int lane = threadIdx.x & 63;
    int node = blockIdx.x * 4 + wave;
    const float* row = h3 + (size_t)node * 192;
    float m = -INFINITY;
    for (int t = lane; t < 192; t += 64) m = fmaxf(m, row[t]);
#pragma unroll
    for (int off = 32; off > 0; off >>= 1) m = fmaxf(m, __shfl_down(m, off, 64));
    if (lane == 0) nm[node] = m;
}

__global__ __launch_bounds__(256) void g_k(const float* __restrict__ nm,
    const float* __restrict__ W3, const float* __restrict__ b3,
    const float* __restrict__ W4, const float* __restrict__ b4,
    float* __restrict__ g)
{
    __shared__ float row[256];
    __shared__ float t1[64];
    int b = blockIdx.x, tid = threadIdx.x;
    row[tid] = nm[b * 256 + tid];
    __syncthreads();
    if (tid < 64) {
        float a = b3[tid];
        for (int k = 0; k < 256; k++) a = fmaf(row[k], W3[k * 64 + tid], a);
        t1[tid] = fmaxf(a, 0.f);
    }
    __syncthreads();
    float a = b4[tid];
    for (int j = 0; j < 64; j++) a = fmaf(t1[j], W4[j * 256 + tid], a);
    g[b * 256 + tid] = 1.f / (1.f + expf(-a));
}

// ======================= masked softmax (parallel, 2-pass; sm1 caches logits in out) ====
__global__ __launch_bounds__(256) void sm1_k(const float* __restrict__ mask,
    const float* __restrict__ g, const float* __restrict__ h3, float* __restrict__ part,
    float* __restrict__ out)
{
    int b = blockIdx.x, s = blockIdx.y, tid = threadIdx.x;
    float l[24];
#pragma unroll
    for (int t = 0; t < 24; t++) {
        int i = s * 6144 + t * 256 + tid;
        size_t idx = (size_t)b * 49152 + i;
        float mk = mask[idx];
        l[t] = (mk == 0.f) ? -1e5f : g[b * 256 + i / 192] * h3[idx];
        out[idx] = l[t];
    }
    float m = -INFINITY;
#pragma unroll
    for (int t = 0; t < 24; t++) m = fmaxf(m, l[t]);
    __shared__ float red[256];
    red[tid] = m; __syncthreads();
    for (int st = 128; st > 0; st >>= 1) { if (tid < st) red[tid] = fmaxf(red[tid], red[tid + st]); __syncthreads(); }
    m = red[0]; __syncthreads();
    float z = 0.f;
#pragma unroll
    for (int t = 0; t < 24; t++) z += expf(l[t] - m);
    red[tid] = z; __syncthreads();
    for (int st = 128; st > 0; st >>= 1) { if (tid < st) red[tid] += red[tid + st]; __syncthreads(); }
    if (tid == 0) { part[(b * 8 + s) * 2] = m; part[(b * 8 + s) * 2 + 1] = red[0]; }
}

__global__ void sm2_k(const float* __restrict__ part, float* __restrict__ mz)
{
    int b = threadIdx.x;
    if (b >= 64) return;
    float M = -INFINITY;
    for (int s = 0; s < 8; s++) M = fmaxf(M, part[(b * 8 + s) * 2]);
    float Z = 0.f;
    for (int s = 0; s < 8; s++) Z += part[(b * 8 + s) * 2 + 1] * expf(part[(b * 8 + s) * 2] - M);
    mz[b * 2] = M;
    mz[b * 2 + 1] = 1.f / Z;
}

__global__ __launch_bounds__(256) void sm3_k(const float* __restrict__ mz,
    float* __restrict__ out)
{
    int b = blockIdx.x, s = blockIdx.y, tid = threadIdx.x;
    float M = mz[b * 2], invZ = mz[b * 2 + 1];
#pragma unroll
    for (int t = 0; t < 24; t++) {
        int i = s * 6144 + t * 256 + tid;
        size_t idx = (size_t)b * 49152 + i;
        float v = out[idx];
        out[idx] = expf(v - M) * invZ;
    }
}

// ======================= launcher =======================
extern "C" void kernel_launch(void* const* d_in, const int* in_sizes, int n_in,
                              void* d_out, int out_size, void* d_ws, size_t ws_size,
                              hipStream_t stream)
{
    const float* ns   = (const float*)d_in[0];
    const float* es   = (const float*)d_in[1];
    const float* dm   = (const float*)d_in[2];
    const float* mask = (const float*)d_in[3];
    const int*   src  = (const int*)d_in[4];
    const float* Wm1 = (const float*)d_in[6],  *bm1 = (const float*)d_in[7];
    const float* Wu1 = (const float*)d_in[8],  *bu1 = (const float*)d_in[9];
    const float* bng1= (const float*)d_in[10], *bnb1= (const float*)d_in[11];
    const float* Wx1 = (const float*)d_in[12], *bx1 = (const float*)d_in[13];
    const float* Wm2 = (const float*)d_in[14], *bm2 = (const float*)d_in[15];
    const float* Wu2 = (const float*)d_in[16], *bu2 = (const float*)d_in[17];
    const float* bng2= (const float*)d_in[18], *bnb2= (const float*)d_in[19];
    const float* Wx2 = (const float*)d_in[20], *bx2 = (const float*)d_in[21];
    const float* Wm3 = (const float*)d_in[22], *bm3 = (const float*)d_in[23];
    const float* Wu3 = (const float*)d_in[24], *bu3 = (const float*)d_in[25];
    const float* bng3= (const float*)d_in[26], *bnb3= (const float*)d_in[27];
    const float* Wx3 = (const float*)d_in[28], *bx3 = (const float*)d_in[29];
    const float* W1 = (const float*)d_in[30], *b1 = (const float*)d_in[31];
    const float* W2 = (const float*)d_in[32], *b2 = (const float*)d_in[33];
    const float* W3 = (const float*)d_in[34], *b3 = (const float*)d_in[35];
    const float* W4 = (const float*)d_in[36], *b4 = (const float*)d_in[37];
    float* out = (float*)d_out;

    const int N = NNODE;
    char* base = (char*)d_ws;
    size_t off = 0;
    auto alloc = [&](size_t bytes) -> void* {
        void* p = base + off;
        off = (off + bytes + 255) & ~(size_t)255;
        return p;
    };
    us16* Xh = (us16*)alloc((size_t)N * 1728 * 2);
    us16* Xl = (us16*)alloc((size_t)N * 1728 * 2);
    float* H2   = (float*)alloc((size_t)N * 1216 * 4);   // [Hsrc|Hdst|u_partial]
    us16* uh = (us16*)alloc((size_t)N * 384 * 2);
    us16* ul = (us16*)alloc((size_t)N * 384 * 2);
    us16* dmh = (us16*)alloc((size_t)N * 256 * 2);
    us16* dml = (us16*)alloc((size_t)N * 256 * 2);
    float* h3b  = (float*)alloc((size_t)N * 192 * 4);
    float* d2f  = (float*)alloc((size_t)N * 32 * 4);
    float* part = (float*)alloc((size_t)512 * 384 * 4);
    float* scale= (float*)alloc(384 * 4);
    float* shift= (float*)alloc(384 * 4);
    float* bias2= (float*)alloc(384 * 4);
    float* b12  = (float*)alloc(32 * 4);
    float* biasMU1 = (float*)alloc(640 * 4);
    float* biasMU2 = (float*)alloc(1216 * 4);
    float* biasMU3 = (float*)alloc(960 * 4);
    float* nm   = (float*)alloc((size_t)N * 4);
    float* gbuf = (float*)alloc((size_t)N * 4);
    float* smp  = (float*)alloc(64 * 8 * 2 * 4);
    float* smz  = (float*)alloc(64 * 2 * 4);
    auto aw = [&](size_t elems) -> us16* { return (us16*)alloc(elems * 2); };
    us16 *BM1h = aw((size_t)640 * 4 * 32),    *BM1l = aw((size_t)640 * 4 * 32);
    us16 *BA1h = aw((size_t)384 * 12 * 32),   *BA1l = aw((size_t)384 * 12 * 32);
    us16 *BX1h = aw((size_t)384 * 12 * 32),   *BX1l = aw((size_t)384 * 12 * 32);
    us16 *BM2h = aw((size_t)1280 * 14 * 32),  *BM2l = aw((size_t)1280 * 14 * 32);
    us16 *BA2h = aw((size_t)384 * 40 * 32),   *BA2l = aw((size_t)384 * 40 * 32);
    us16 *BX2h = aw((size_t)384 * 12 * 32),   *BX2l = aw((size_t)384 * 12 * 32);
    us16 *BM3h = aw((size_t)1024 * 12 * 32),  *BM3l = aw((size_t)1024 * 12 * 32);
    us16 *BA3h = aw((size_t)192 * 36 * 32),   *BA3l = aw((size_t)192 * 36 * 32);
    us16 *BX3h = aw((size_t)192 * 6 * 32),    *BX3l = aw((size_t)192 * 6 * 32);
    us16 *B12h = aw((size_t)64 * 8 * 32),     *B12l = aw((size_t)64 * 8 * 32);

    auto gp = [](size_t n) { return dim3((unsigned)((n + 255) / 256)); };
    auto fsec = [](us16* b, int c0, int KC) { return b + (size_t)(c0 / 16) * KC * 512; };

    // ---- fused fragment prep descriptors ----
    FrPack pk;
    int nd = 0, blk = 0;
    auto addD = [&](const float* W, us16* Bh, us16* Bl, int ldW, int Kv, int Nv, int Na, int KC, int mode, int cin) {
        pk.d[nd] = {W, Bh, Bl, ldW, Kv, Nv, Na, KC, mode, cin, blk};
        blk += (Na * KC * 32 + 255) / 256;
        nd++;
    };
    addD(Wm1,             fsec(BM1h,0,4),    fsec(BM1l,0,4),    128, 128, 128, 128, 4, 0, 0);
    addD(Wm1 + 128*128,   fsec(BM1h,128,4),  fsec(BM1l,128,4),  128, 128, 128, 128, 4, 0, 0);
    addD(Wu1,             fsec(BM1h,256,4),  fsec(BM1l,256,4),  384, 128, 384, 384, 4, 0, 0);
    addD(Wu1,             BA1h, BA1l,        0,   0,   384, 384, 12, 1, 128);
    addD(Wm2,             fsec(BM2h,0,14),   fsec(BM2l,0,14),   416, 416, 416, 416, 14, 0, 0);
    addD(Wm2 + 416*416,   fsec(BM2h,416,14), fsec(BM2l,416,14), 416, 416, 416, 416, 14, 0, 0);
    addD(Wu2,             fsec(BM2h,832,14), fsec(BM2l,832,14), 384, 416, 384, 384, 14, 0, 0);
    addD(nullptr,         fsec(BM2h,1216,14),fsec(BM2l,1216,14),0,   0,   0,   64,  14, 2, 0);
    addD(Wu2,             BA2h, BA2l,        0,   0,   384, 384, 40, 1, 416);
    addD(Wm3,             fsec(BM3h,0,12),   fsec(BM3l,0,12),   384, 384, 384, 384, 12, 0, 0);
    addD(Wm3 + 384*384,   fsec(BM3h,384,12), fsec(BM3l,384,12), 384, 384, 384, 384, 12, 0, 0);
    addD(Wu3,             fsec(BM3h,768,12), fsec(BM3l,768,12), 192, 384, 192, 192, 12, 0, 0);
    addD(nullptr,         fsec(BM3h,960,12), fsec(BM3l,960,12), 0,   0,   0,   64,  12, 2, 0);
    addD(Wu3,             BA3h, BA3l,        0,   0,   192, 192, 36, 1, 384);
    pk.nd = nd;

    // ---- input splits + preps ----
    csplit2_k<<<8192 + 16384, 256, 0, stream>>>(ns, Xh, Xl, dm, dmh, dml);
    prep_fr_all<<<blk, 256, 0, stream>>>(pk);
    w12frag_k<<<gp(64 * 8 * 32), 256, 0, stream>>>(W1, W2, B12h, B12l);
    bias12_k<<<1, 32, 0, stream>>>(b1, W2, b2, b12);
    prep_biasMU<<<gp(640), 256, 0, stream>>>(bm1, bu1, biasMU1, 128, 384);
    prep_biasMU<<<gp(1216), 256, 0, stream>>>(bm2, bu2, biasMU2, 416, 384);
    prep_biasMU<<<gp(960), 256, 0, stream>>>(bm3, bu3, biasMU3, 384, 192);

    // ---- d2 = dm @ W12 + b12 ----
    mgemm9<0, 0, 0, 1, 0><<<256, 256, 0, stream>>>(1, dmh, dml, 256, 256, B12h, B12l, 8,
        nullptr, 0, d2f, nullptr, nullptr, 32, 32, b12, nullptr, 0);

    // ================= layer 1 (cin=128, X ld 512, H2 ld 640) =================
    mgemm9<0, 0, 0, 2, 0><<<256 * 5, 256, 0, stream>>>(5, Xh, Xl, 512, 128, BM1h, BM1l, 4,
        nullptr, 0, H2, nullptr, nullptr, 640, 640, biasMU1, nullptr, 0);
    agg2_k<<<dim3(64, 2, 4), 256, 0, stream>>>(H2, es, src, Wm1 + 2 * 128 * 128, Xh, Xl, 128, 640, 512, 128);
    mgemm9<0, 1, 1, 2, 1><<<256 * 3, 256, 0, stream>>>(3, Xh + 128, Xl + 128, 512, 384, BA1h, BA1l, 12,
        H2 + 256, 640, nullptr, uh, ul, 384, 384, nullptr, part, 384);
    bnstats2p_k<<<6, 256, 0, stream>>>(part, bng1, bnb1, scale, shift, 384);
    fusedwx_k<<<576 + 384, 256, 0, stream>>>(Wx1, scale, shift, bx1, BX1h, BX1l, 384, 384, 12, 576, bias2);
    mgemm9<1, 1, 0, 2, 0><<<256 * 3, 256, 0, stream>>>(3, uh, ul, 384, 384, BX1h, BX1l, 12,
        nullptr, 0, nullptr, Xh, Xl, 1728, 384, bias2, nullptr, 0);   // h2a -> X2[0:384)
    csplit_k<<<gp((size_t)N * 32), 256, 0, stream>>>(d2f, 32, 32, Xh, Xl, 1728, 384);  // d2 -> X2[384:416)

    // ================= layer 2 (cin=416, X ld 1728, H2 ld 1216) =================
    mgemm9<0, 0, 0, 2, 0><<<256 * 10, 256, 0, stream>>>(10, Xh, Xl, 1728, 416, BM2h, BM2l, 14,
        nullptr, 0, H2, nullptr, nullptr, 1216, 1216, biasMU2, nullptr, 0);
    agg2_k<<<dim3(64, 7, 4), 256, 0, stream>>>(H2, es, src, Wm2 + 2 * 416 * 416, Xh, Xl, 416, 1216, 1728, 416);
    mgemm9<0, 1, 1, 2, 1><<<256 * 3, 256, 0, stream>>>(3, Xh + 416, Xl + 416, 1728, 1248, BA2h, BA2l, 40,
        H2 + 832, 1216, nullptr, uh, ul, 384, 384, nullptr, part, 384);
    bnstats2p_k<<<6, 256, 0, stream>>>(part, bng2, bnb2, scale, shift, 384);
    fusedwx_k<<<576 + 384, 256, 0, stream>>>(Wx2, scale, shift, bx2, BX2h, BX2l, 384, 384, 12, 576, bias2);
    mgemm9<1, 1, 0, 2, 0><<<256 * 3, 256, 0, stream>>>(3, uh, ul, 384, 384, BX2h, BX2l, 12,
        nullptr, 0, nullptr, Xh, Xl, 1536, 384, bias2, nullptr, 0);   // h3-in -> X3[0:384)

    // ================= layer 3 (cin=384, X ld 1536, H2 ld 960) =================
    mgemm9<0, 0, 0, 2, 0><<<256 * 8, 256, 0, stream>>>(8, Xh, Xl, 1536, 384, BM3h, BM3l, 12,
        nullptr, 0, H2, nullptr, nullptr, 960, 960, biasMU3, nullptr, 0);
    agg2_k<<<dim3(64, 6, 4), 256, 0, stream>>>(H2, es, src, Wm3 + 2 * 384 * 384, Xh, Xl, 384, 960, 1536, 384);
    mgemm9<0, 1, 1, 1, 1><<<256 * 3, 256, 0, stream>>>(3, Xh + 384, Xl + 384, 1536, 1152, BA3h, BA3l, 36,
        H2 + 768, 960, nullptr, uh, ul, 192, 192, nullptr, part, 192);
    bnstats2p_k<<<3, 256, 0, stream>>>(part, bng3, bnb3, scale, shift, 192);
    fusedwx_k<<<144 + 192, 256, 0, stream>>>(Wx3, scale, shift, bx3, BX3h, BX3l, 192, 192, 6, 144, bias2);
    mgemm9<2, 0, 0, 1, 0><<<256 * 3, 256, 0, stream>>>(3, uh, ul, 192, 192, BX3h, BX3l, 6,
        nullptr, 0, h3b, nullptr, nullptr, 192, 192, bias2, nullptr, 0);

    // ---- head ----
    rowmax_k<<<N / 4, 256, 0, stream>>>(h3b, nm);
    g_k<<<64, 256, 0, stream>>>(nm, W3, b3, W4, b4, gbuf);
    sm1_k<<<dim3(64, 8), 256, 0, stream>>>(mask, gbuf, h3b, smp, out);
    sm2_k<<<1, 64, 0, stream>>>(smp, smz);
    sm3_k<<<dim3(64, 8), 256, 0, stream>>>(smz, out);
}